// Round 6
// baseline (588.274 us; speedup 1.0000x reference)
//
#include <hip/hip_runtime.h>

// ---------------------------------------------------------------------------
// Transformer block w/ SimilarityMaps branch. fp32 inputs/outputs; weights
// canonicalized to bf16; GEMMs + attention on MFMA (16x16x32 bf16).
// B=8 N=1024 C=768 H=12 hd=64 K_PARTS=64 HID=3072. Tokens M = 8192.
// Round 14: add gemm256 (256x256 tile, 8 waves, BK=64, dbuf 128KB LDS,
//   XOR-swizzled LDS via pre-swizzled global source, counted vmcnt(8),
//   setprio) for qkv/qkv2/fc1. R5 counters proved the 128x128 geometry is
//   LDS-throughput-bound (~2.3k LDS-cyc per 64-K vs 640 MFMA-cyc); barrier
//   and prefetch tuning were all neutral. Bigger per-wave tiles cut LDS
//   bytes/FLOP 1.35x and the swizzle removes read conflicts.
// ---------------------------------------------------------------------------

typedef unsigned short u16;
typedef unsigned int   u32;
typedef __attribute__((ext_vector_type(8))) short short8;       // bf16 x8 frag
typedef __attribute__((ext_vector_type(8))) unsigned short ushort8v;
typedef __attribute__((ext_vector_type(4))) float f32x4;        // MFMA accum

#define F_GELU     1
#define F_ROWSCALE 2
#define F_RES1     4    // bf16 residual (res1)
#define F_RESF     8    // fp32 residual (resf)
#define F_OUTB     16   // write bf16 to out
#define F_OUTF     32   // write fp32 to outf
#define F_BIAS     64   // fp32 bias

__device__ __forceinline__ float bf2f(u32 b) { return __uint_as_float(b << 16); }
__device__ __forceinline__ u16 f2bf(float f) {
    u32 u = __float_as_uint(f);
    u32 r = u + 0x7fffu + ((u >> 16) & 1u);   // RNE
    return (u16)(r >> 16);
}
__device__ __forceinline__ u16 f2bf_fast(float f) {
    return (u16)((__float_as_uint(f) + 0x8000u) >> 16);
}
__device__ __forceinline__ float gelu_exact(float v) {
    return 0.5f * v * (1.0f + erff(v * 0.70710678118654752440f));
}
// tanh-form GELU (max abs dev from exact ~3e-3; cheap: 1 transcendental)
__device__ __forceinline__ float gelu_fast(float x) {
    float u = 0.79788456080286535588f * (x + 0.044715f * x * x * x);
    float e = __builtin_amdgcn_exp2f(u * 2.88539008177792681472f);  // exp(2u)
    float t = 1.0f - 2.0f / (e + 1.0f);
    return 0.5f * x * (1.0f + t);
}

// async global->LDS, 16 B per lane; lds base must be wave-uniform
__device__ __forceinline__ void gload16(const u16* g, u16* l) {
    __builtin_amdgcn_global_load_lds(
        (const __attribute__((address_space(1))) u32*)g,
        (__attribute__((address_space(3))) u32*)l, 16, 0, 0);
}

// ---------------- fp32 -> bf16 weight canonicalization (all 8, fused) ------
struct ConvArgs {
    const float* src[8];
    u16*         dst[8];
    int          nblk[9];   // cumulative block offsets
    int          n[8];
};

__global__ __launch_bounds__(256)
void conv_all_k(ConvArgs a)
{
    const int b = blockIdx.x;
    int i = 0;
    #pragma unroll
    for (int j = 0; j < 7; j++) if (b >= a.nblk[j + 1]) i = j + 1;
    const int base = (b - a.nblk[i]) * 1024 + threadIdx.x * 4;
    if (base >= a.n[i]) return;
    float4 v = *(const float4*)(a.src[i] + base);
    ushort4 o;
    o.x = f2bf(v.x); o.y = f2bf(v.y); o.z = f2bf(v.z); o.w = f2bf(v.w);
    *(ushort4*)(a.dst[i] + base) = o;
}

__device__ __forceinline__ float block_sum(float v, float* red) {
    #pragma unroll
    for (int off = 32; off > 0; off >>= 1) v += __shfl_down(v, off);
    __syncthreads();
    if ((threadIdx.x & 63) == 0) red[threadIdx.x >> 6] = v;
    __syncthreads();
    return red[0] + red[1] + red[2] + red[3];
}

// ---------------- LayerNorm over 768 (fp32 in, bf16 out), opt 1/||y|| ------
template<bool NORM>
__global__ __launch_bounds__(256)
void ln_k(const float* __restrict__ xin, const float* __restrict__ g,
          const float* __restrict__ bta, u16* __restrict__ out,
          float* __restrict__ invnorm)
{
    __shared__ float red[4];
    const int row = blockIdx.x, t = threadIdx.x;
    float v[3];
    #pragma unroll
    for (int i = 0; i < 3; i++)
        v[i] = xin[(size_t)row * 768 + t + i * 256];
    float tot = block_sum(v[0] + v[1] + v[2], red);
    float mu  = tot * (1.0f / 768.0f);
    float d0 = v[0] - mu, d1 = v[1] - mu, d2 = v[2] - mu;
    float tot2 = block_sum(d0 * d0 + d1 * d1 + d2 * d2, red);
    float rstd = rsqrtf(tot2 * (1.0f / 768.0f) + 1e-5f);
    float ss = 0.0f;
    #pragma unroll
    for (int i = 0; i < 3; i++) {
        int c = t + i * 256;
        float yy = (v[i] - mu) * rstd * g[c] + bta[c];
        out[(size_t)row * 768 + c] = f2bf(yy);
        ss += yy * yy;
    }
    if constexpr (NORM) {
        float tot3 = block_sum(ss, red);
        if (t == 0) invnorm[row] = rsqrtf(tot3);
    }
}

// ---------------- P row-normalize: Pn = bf16(P / ||P_row||) ----------------
__global__ __launch_bounds__(256)
void pn_k(const float* __restrict__ P, u16* __restrict__ Pn)
{
    __shared__ float red[4];
    const int row = blockIdx.x, t = threadIdx.x;
    float v[3];
    #pragma unroll
    for (int i = 0; i < 3; i++)
        v[i] = P[(size_t)row * 768 + t + i * 256];
    float tot = block_sum(v[0]*v[0] + v[1]*v[1] + v[2]*v[2], red);
    float inv = rsqrtf(tot);
    #pragma unroll
    for (int i = 0; i < 3; i++)
        Pn[(size_t)row * 768 + t + i * 256] = f2bf(v[i] * inv);
}

// ---------------- MFMA GEMM 256x256: C[M,N] = A[M,K] * W[N,K]^T ------------
// 512 threads = 8 waves (2 M-rows x 4 N-cols), each wave owns 128x64 output
// (acc[8][4] f32x4). BK=64. Double-buffered LDS: As/Bs[2][256x64] = 128 KB.
// LDS XOR-swizzle (col16 ^= row&7) applied on BOTH sides: staging pre-swizzles
// the per-lane GLOBAL source (LDS dest stays linear for global_load_lds);
// ds_read applies the same XOR -> conflict-minimal fragment reads.
// Counted vmcnt(8): next tile's 8 loads stay in flight across the barrier.
// Requires M%256==0, N%256==0, K%64==0, gridDim.y%8==0.
template<int FLAGS>
__global__ __launch_bounds__(512, 2)
void gemm256(const u16* __restrict__ A, const u16* __restrict__ W,
             const float* __restrict__ bias, u16* __restrict__ out,
             int M, int N, int K)
{
    __shared__ u16 As[2][16384];   // [buf][256 rows x 64 cols]
    __shared__ u16 Bs[2][16384];
    const int t = threadIdx.x;
    const int wave = t >> 6, lane = t & 63;
    const int quad = lane >> 4, r16 = lane & 15;
    const int wr = wave >> 2, wc = wave & 3;   // wave position: 2M x 4N

    // XCD-chunked block order (col-major within chunk for W reuse)
    const int nbx = gridDim.x, nby = gridDim.y;
    const int orig = blockIdx.x + blockIdx.y * nbx;
    const int Rc   = nby >> 3;                 // tile-rows per XCD
    const int xcd  = orig & 7, loc = orig >> 3;
    const int m0 = (xcd * Rc + (loc % Rc)) * 256;
    const int n0 = (loc / Rc) * 256;
    const int NT = K >> 6;

    f32x4 acc[8][4];
    #pragma unroll
    for (int i = 0; i < 8; i++)
        #pragma unroll
        for (int j = 0; j < 4; j++)
            acc[i][j] = (f32x4){0.f, 0.f, 0.f, 0.f};

    // staging lane geometry: per issue i (0..3), wave covers rows
    // [i*64 + wave*8, +8), lane covers row i*64+wave*8+(lane>>3),
    // 16B at col16 = lane&7 (linear LDS). Global source col16 is
    // pre-swizzled: (lane&7) ^ (row&7) where row&7 == (lane>>3)&7.
    const int srow = wave * 8 + (lane >> 3);            // + i*64
    const int scol = ((lane & 7) ^ ((lane >> 3) & 7)) * 8;

    const u16* Abase = A + (size_t)m0 * K;
    const u16* Wbase = W + (size_t)n0 * K;

    // prologue: stage tiles 0 and 1 (8 gload16 per thread per tile)
    #pragma unroll
    for (int i = 0; i < 4; i++)
        gload16(Abase + (size_t)(i * 64 + srow) * K + scol,
                &As[0][i * 4096 + wave * 512]);
    #pragma unroll
    for (int i = 0; i < 4; i++)
        gload16(Wbase + (size_t)(i * 64 + srow) * K + scol,
                &Bs[0][i * 4096 + wave * 512]);
    if (NT > 1) {
        #pragma unroll
        for (int i = 0; i < 4; i++)
            gload16(Abase + (size_t)(i * 64 + srow) * K + 64 + scol,
                    &As[1][i * 4096 + wave * 512]);
        #pragma unroll
        for (int i = 0; i < 4; i++)
            gload16(Wbase + (size_t)(i * 64 + srow) * K + 64 + scol,
                    &Bs[1][i * 4096 + wave * 512]);
    }

    for (int kt = 0; kt < NT; kt++) {
        const int c = kt & 1;
        // drain current tile's 8 loads; keep next tile's 8 in flight
        if (kt + 1 < NT)
            asm volatile("s_waitcnt vmcnt(8)\n\ts_barrier" ::: "memory");
        else
            asm volatile("s_waitcnt vmcnt(0)\n\ts_barrier" ::: "memory");

        #pragma unroll
        for (int ks = 0; ks < 2; ks++) {
            short8 bfr[4], af[8];
            #pragma unroll
            for (int j = 0; j < 4; j++) {
                const int br = wc * 64 + j * 16 + r16;
                bfr[j] = *(const short8*)
                    &Bs[c][br * 64 + (((ks * 4 + quad) ^ (br & 7)) * 8)];
            }
            #pragma unroll
            for (int i = 0; i < 8; i++) {
                const int ar = wr * 128 + i * 16 + r16;
                af[i] = *(const short8*)
                    &As[c][ar * 64 + (((ks * 4 + quad) ^ (ar & 7)) * 8)];
            }
            __builtin_amdgcn_s_setprio(1);
            #pragma unroll
            for (int i = 0; i < 8; i++)
                #pragma unroll
                for (int j = 0; j < 4; j++)
                    acc[i][j] = __builtin_amdgcn_mfma_f32_16x16x32_bf16(
                        af[i], bfr[j], acc[i][j], 0, 0, 0);
            __builtin_amdgcn_s_setprio(0);
        }
        // all waves done reading buf c before DMA overwrites it
        asm volatile("s_barrier" ::: "memory");
        if (kt + 2 < NT) {
            const int k0 = (kt + 2) * 64;
            #pragma unroll
            for (int i = 0; i < 4; i++)
                gload16(Abase + (size_t)(i * 64 + srow) * K + k0 + scol,
                        &As[c][i * 4096 + wave * 512]);
            #pragma unroll
            for (int i = 0; i < 4; i++)
                gload16(Wbase + (size_t)(i * 64 + srow) * K + k0 + scol,
                        &Bs[c][i * 4096 + wave * 512]);
        }
    }

    // ---- epilogue: wave-private fp32 repack (stride 68, conflict-free) ----
    float* myl = (float*)&As[0][0] + wave * 1088;   // 16 rows x 68 cols fp32
    float bj[4];
    #pragma unroll
    for (int j = 0; j < 4; j++) {
        if constexpr (FLAGS & F_BIAS) bj[j] = bias[n0 + wc * 64 + j * 16 + r16];
        else bj[j] = 0.0f;
    }
    const int row = lane >> 2, seg = (lane & 3) * 16;

    #pragma unroll
    for (int i = 0; i < 8; i++) {
        #pragma unroll
        for (int j = 0; j < 4; j++)
            #pragma unroll
            for (int r = 0; r < 4; r++) {
                float v = acc[i][j][r] + bj[j];
                if constexpr (FLAGS & F_GELU) v = gelu_fast(v);
                myl[(quad * 4 + r) * 68 + j * 16 + r16] = v;
            }
        float v[16];
        #pragma unroll
        for (int k4 = 0; k4 < 4; k4++) {
            float4 f = *(const float4*)&myl[row * 68 + seg + k4 * 4];
            v[k4 * 4 + 0] = f.x; v[k4 * 4 + 1] = f.y;
            v[k4 * 4 + 2] = f.z; v[k4 * 4 + 3] = f.w;
        }
        const int m = m0 + wr * 128 + i * 16 + row;
        const size_t idx = (size_t)m * N + n0 + wc * 64 + seg;
        ushort8v o0, o1;
        #pragma unroll
        for (int k = 0; k < 8; k++) { o0[k] = f2bf(v[k]); o1[k] = f2bf(v[k + 8]); }
        *(ushort8v*)(out + idx) = o0;
        *(ushort8v*)(out + idx + 8) = o1;
    }
}

// ---------------- MFMA GEMM: C[M,N] = A[M,K] * W[N,K]^T (+epilogue) --------
// 128x128 tile, BK=32; 4 waves, each a 64x64 sub-tile. Triple-buffered LDS,
// 2-deep prefetch, one barrier per K-iter. XCD-chunked block order with
// intra-chunk col-grouping (G=6). Used for the N=768 / K<=64 GEMMs.
template<int FLAGS>
__global__ __launch_bounds__(256)
void gemm_mfma(const u16* __restrict__ A, const u16* __restrict__ W,
               const float* __restrict__ bias,
               const u16* __restrict__ res1, const float* __restrict__ resf,
               u16* __restrict__ out, float* __restrict__ outf,
               int M, int N, int K)
{
    __shared__ u16 smem[3][8192];        // [buf][ As 4096 | Bs 4096 ] = 48 KB
    const int t = threadIdx.x;
    const int wave = t >> 6, lane = t & 63;
    const int nbx  = gridDim.x;
    const int orig = blockIdx.x + blockIdx.y * nbx;
    const int cpx  = (nbx * gridDim.y) >> 3;   // wgs per XCD chunk
    const int xcd  = orig & 7, loc = orig >> 3;
    const int Rc   = cpx / nbx;                // rows per chunk (8 here)
    const int gsz  = 6 * Rc;                   // wgs per col-group
    const int grp  = loc / gsz;
    const int rem  = loc - grp * gsz;
    const int ccol = grp * 6 + rem % 6;
    const int crow = xcd * Rc + rem / 6;
    const int m0 = crow * 128, n0 = ccol * 128;
    const int Wm = (wave >> 1) * 64, Wn = (wave & 1) * 64;
    const int rr = lane >> 2, cc = (lane & 3) * 8;
    const int quad = lane >> 4, r16 = lane & 15;
    const int NK = K >> 5;

    f32x4 acc[4][4];
    #pragma unroll
    for (int i = 0; i < 4; i++)
        #pragma unroll
        for (int j = 0; j < 4; j++)
            acc[i][j] = (f32x4){0.f, 0.f, 0.f, 0.f};

    // prologue: stage k-tiles 0 and 1 into bufs 0,1 (order matters for vmcnt)
    #pragma unroll
    for (int c = 0; c < 2; c++) {
        const int chunk = wave * 2 + c;
        const int row = chunk * 16 + rr;
        gload16(A + (size_t)(m0 + row) * K + cc, &smem[0][chunk * 512]);
        gload16(W + (size_t)(n0 + row) * K + cc, &smem[0][4096 + chunk * 512]);
    }
    if (NK > 1) {
        #pragma unroll
        for (int c = 0; c < 2; c++) {
            const int chunk = wave * 2 + c;
            const int row = chunk * 16 + rr;
            gload16(A + (size_t)(m0 + row) * K + 32 + cc, &smem[1][chunk * 512]);
            gload16(W + (size_t)(n0 + row) * K + 32 + cc, &smem[1][4096 + chunk * 512]);
        }
    }

    for (int kt = 0; kt < NK; kt++) {
        const int cur = kt % 3;
        if (kt + 1 < NK)
            asm volatile("s_waitcnt vmcnt(4)\n\ts_barrier" ::: "memory");
        else
            asm volatile("s_waitcnt vmcnt(0)\n\ts_barrier" ::: "memory");
        if (kt + 2 < NK) {
            const int k0 = (kt + 2) * 32;
            const int nb = (kt + 2) % 3;
            #pragma unroll
            for (int c = 0; c < 2; c++) {
                const int chunk = wave * 2 + c;
                const int row = chunk * 16 + rr;
                gload16(A + (size_t)(m0 + row) * K + k0 + cc,
                        &smem[nb][chunk * 512]);
                gload16(W + (size_t)(n0 + row) * K + k0 + cc,
                        &smem[nb][4096 + chunk * 512]);
            }
        }
        short8 af[4], bfr[4];
        #pragma unroll
        for (int i = 0; i < 4; i++) {
            af[i]  = *(const short8*)&smem[cur][(Wm + i * 16 + r16) * 32 + quad * 8];
            bfr[i] = *(const short8*)&smem[cur][4096 + (Wn + i * 16 + r16) * 32 + quad * 8];
        }
        #pragma unroll
        for (int i = 0; i < 4; i++)
            #pragma unroll
            for (int j = 0; j < 4; j++)
                acc[i][j] = __builtin_amdgcn_mfma_f32_16x16x32_bf16(
                    af[i], bfr[j], acc[i][j], 0, 0, 0);
    }
    __syncthreads();

    // ---- epilogue: wave-private fp32 repack (no cross-wave sync) ----
    float* myl = (float*)&smem[0][0] + wave * 1088;   // 16 rows x 68 cols fp32
    float bj[4];
    #pragma unroll
    for (int j = 0; j < 4; j++) {
        if constexpr (FLAGS & F_BIAS) bj[j] = bias[n0 + Wn + j * 16 + r16];
        else bj[j] = 0.0f;
    }
    const int row = lane >> 2, seg = (lane & 3) * 16;

    #pragma unroll
    for (int i = 0; i < 4; i++) {
        #pragma unroll
        for (int j = 0; j < 4; j++)
            #pragma unroll
            for (int r = 0; r < 4; r++) {
                float v = acc[i][j][r] + bj[j];
                if constexpr (FLAGS & F_GELU) v = gelu_fast(v);
                myl[(quad * 4 + r) * 68 + j * 16 + r16] = v;
            }
        float v[16];
        #pragma unroll
        for (int k4 = 0; k4 < 4; k4++) {
            float4 f = *(const float4*)&myl[row * 68 + seg + k4 * 4];
            v[k4 * 4 + 0] = f.x; v[k4 * 4 + 1] = f.y;
            v[k4 * 4 + 2] = f.z; v[k4 * 4 + 3] = f.w;
        }
        const int m = m0 + Wm + i * 16 + row;
        const size_t idx = (size_t)m * N + n0 + Wn + seg;
        if constexpr (FLAGS & F_RES1) {
            ushort8v r0 = *(const ushort8v*)(res1 + idx);
            ushort8v r1 = *(const ushort8v*)(res1 + idx + 8);
            #pragma unroll
            for (int k = 0; k < 8; k++) { v[k] += bf2f(r0[k]); v[k + 8] += bf2f(r1[k]); }
        }
        if constexpr (FLAGS & F_RESF) {
            #pragma unroll
            for (int k4 = 0; k4 < 4; k4++) {
                float4 f = *(const float4*)(resf + idx + k4 * 4);
                v[k4 * 4 + 0] += f.x; v[k4 * 4 + 1] += f.y;
                v[k4 * 4 + 2] += f.z; v[k4 * 4 + 3] += f.w;
            }
        }
        if constexpr (FLAGS & F_OUTB) {
            ushort8v o0, o1;
            #pragma unroll
            for (int k = 0; k < 8; k++) { o0[k] = f2bf(v[k]); o1[k] = f2bf(v[k + 8]); }
            *(ushort8v*)(out + idx) = o0;
            *(ushort8v*)(out + idx + 8) = o1;
        }
        if constexpr (FLAGS & F_OUTF) {
            #pragma unroll
            for (int k4 = 0; k4 < 4; k4++) {
                float4 f = {v[k4 * 4 + 0], v[k4 * 4 + 1], v[k4 * 4 + 2], v[k4 * 4 + 3]};
                *(float4*)(outf + idx + k4 * 4) = f;
            }
        }
    }
}

// ---------------- small fp32 GEMM (64x64 tiles) for the K-parts branch -----
template<int BM, int BN, int FLAGS>
__global__ __launch_bounds__(256)
void gemm_k(const u16* __restrict__ A, const u16* __restrict__ W,
            const float* __restrict__ bias, const float* __restrict__ rowscale,
            const u16* __restrict__ res1, const float* __restrict__ resf,
            u16* __restrict__ out, float* __restrict__ outf,
            int M, int N, int K)
{
    constexpr int RM = BM / 16, RN = BN / 16;
    __shared__ float Asm[16][BM + 4];
    __shared__ float Wsm[16][BN + 4];
    const int t  = threadIdx.x;
    const int tx = t & 15, ty = t >> 4;
    const int m0 = blockIdx.y * BM, n0 = blockIdx.x * BN;

    float acc[RM][RN];
    #pragma unroll
    for (int i = 0; i < RM; i++)
        #pragma unroll
        for (int j = 0; j < RN; j++) acc[i][j] = 0.0f;

    for (int k0 = 0; k0 < K; k0 += 16) {
        #pragma unroll
        for (int i = 0; i < BM / 64; i++) {
            int f = t + i * 256, r = f >> 2, c4 = (f & 3) << 2;
            uint2 u = *(const uint2*)(A + (size_t)(m0 + r) * K + k0 + c4);
            Asm[c4 + 0][r] = bf2f(u.x & 0xffffu);
            Asm[c4 + 1][r] = bf2f(u.x >> 16);
            Asm[c4 + 2][r] = bf2f(u.y & 0xffffu);
            Asm[c4 + 3][r] = bf2f(u.y >> 16);
        }
        #pragma unroll
        for (int i = 0; i < BN / 64; i++) {
            int f = t + i * 256, r = f >> 2, c4 = (f & 3) << 2;
            uint2 u = *(const uint2*)(W + (size_t)(n0 + r) * K + k0 + c4);
            Wsm[c4 + 0][r] = bf2f(u.x & 0xffffu);
            Wsm[c4 + 1][r] = bf2f(u.x >> 16);
            Wsm[c4 + 2][r] = bf2f(u.y & 0xffffu);
            Wsm[c4 + 3][r] = bf2f(u.y >> 16);
        }
        __syncthreads();
        #pragma unroll
        for (int k = 0; k < 16; k++) {
            float a[RM], w[RN];
            #pragma unroll
            for (int ii = 0; ii < RM; ii += 4) {
                float4 v = *(const float4*)&Asm[k][ty * RM + ii];
                a[ii] = v.x; a[ii + 1] = v.y; a[ii + 2] = v.z; a[ii + 3] = v.w;
            }
            #pragma unroll
            for (int jj = 0; jj < RN; jj += 4) {
                float4 v = *(const float4*)&Wsm[k][tx * RN + jj];
                w[jj] = v.x; w[jj + 1] = v.y; w[jj + 2] = v.z; w[jj + 3] = v.w;
            }
            #pragma unroll
            for (int i = 0; i < RM; i++)
                #pragma unroll
                for (int j = 0; j < RN; j++)
                    acc[i][j] = fmaf(a[i], w[j], acc[i][j]);
        }
        __syncthreads();
    }

    #pragma unroll
    for (int i = 0; i < RM; i++) {
        const int m = m0 + ty * RM + i;
        float rs = 1.0f;
        if constexpr (FLAGS & F_ROWSCALE) rs = rowscale[m];
        #pragma unroll
        for (int jj = 0; jj < RN; jj += 4) {
            const int n = n0 + tx * RN + jj;
            const size_t idx = (size_t)m * N + n;
            float b4[4] = {0.f, 0.f, 0.f, 0.f};
            if constexpr (FLAGS & F_BIAS) {
                float4 bvv = *(const float4*)(bias + n);
                b4[0] = bvv.x; b4[1] = bvv.y; b4[2] = bvv.z; b4[3] = bvv.w;
            }
            float e[4];
            #pragma unroll
            for (int j = 0; j < 4; j++) {
                float v = acc[i][jj + j];
                if constexpr (FLAGS & F_BIAS) v += b4[j];
                if constexpr (FLAGS & F_GELU) v = gelu_exact(v);
                if constexpr (FLAGS & F_ROWSCALE) v *= rs;
                e[j] = v;
            }
            if constexpr (FLAGS & F_OUTB) {
                ushort4 o4;
                o4.x = f2bf(e[0]); o4.y = f2bf(e[1]);
                o4.z = f2bf(e[2]); o4.w = f2bf(e[3]);
                *(ushort4*)(out + idx) = o4;
            }
            if constexpr (FLAGS & F_OUTF) {
                float4 o4 = {e[0], e[1], e[2], e[3]};
                *(float4*)(outf + idx) = o4;
            }
        }
    }
}

// ---------------- MFMA flash attention (bf16, max-free online softmax) ----
// Staging for tile kt+1 (K-DMA + V reg loads) is issued between softmax and
// PV of tile kt, so HBM/L2 latency hides under PV + the next barrier.
__global__ __launch_bounds__(256)
void attn_mfma(const u16* __restrict__ qkv, u16* __restrict__ out)
{
    const int orig = blockIdx.x + blockIdx.y * 8;
    const int wg   = (orig & 7) * 96 + (orig >> 3);
    const int qt = wg & 7;                // 0..7  (128-row q tiles)
    const int bh = wg >> 3;               // 0..95
    const int b = bh / 12, h = bh % 12;
    __shared__ u16 Qs[2 * 128 * 32];      // 16 KB
    __shared__ u16 Ks[2 * 64 * 32];       //  8 KB
    __shared__ u16 Vt[2 * 64 * 32];       //  8 KB  (transposed: rows = d)
    __shared__ u16 Ps[2 * 128 * 32];      // 16 KB; epilogue: 4 waves x 2 x 16x64
    const int t = threadIdx.x;
    const int wave = t >> 6, lane = t & 63;
    const int quad = lane >> 4, r16 = lane & 15;
    const size_t RS = 2304;
    const int tok0 = b * 1024 + qt * 128;
    const u16* qbase = qkv + (size_t)tok0 * RS + h * 64;
    const float SC = 0.125f * 1.44269504088896340736f;   // scale * log2(e)

    #pragma unroll
    for (int c = 0; c < 4; c++) {
        int idx = wave * 4 + c;
        int kc = idx >> 3, rg = idx & 7;
        int row = rg * 16 + (lane >> 2);
        gload16(qbase + (size_t)row * RS + kc * 32 + (lane & 3) * 8,
                &Qs[kc * 4096 + rg * 512]);
    }

    f32x4 O[2][4];
    float lpart[2][4];
    #pragma unroll
    for (int i = 0; i < 2; i++)
        #pragma unroll
        for (int j = 0; j < 4; j++) {
            O[i][j] = (f32x4){0.f, 0.f, 0.f, 0.f};
            lpart[i][j & 3] = 0.0f;
        }

    // staging helpers
    const int kp = t & 63, dg = t >> 6;
    const int vb = (kp >> 5) * 2048 + (kp & 31);
    uint2 vr[4];

    // prologue: stage kt=0 (K-DMA into Ks, V into regs)
    {
        const u16* kbase = qkv + (size_t)(b * 1024) * RS + 768 + h * 64;
        #pragma unroll
        for (int c = 0; c < 2; c++) {
            int idx = wave * 2 + c;
            int kc = idx >> 2, rg = idx & 3;
            int row = rg * 16 + (lane >> 2);
            gload16(kbase + (size_t)row * RS + kc * 32 + (lane & 3) * 8,
                    &Ks[kc * 2048 + rg * 512]);
        }
        const u16* vbase = qkv + (size_t)(b * 1024) * RS + 1536 + h * 64;
        #pragma unroll
        for (int it = 0; it < 4; it++) {
            int d0 = dg * 16 + it * 4;
            vr[it] = *(const uint2*)(vbase + (size_t)kp * RS + d0);
        }
    }

    for (int kt = 0; kt < 16; kt++) {
        // (a) drains K-DMA + V loads (+ Q on first iter); gates Vt/Ps reuse
        __syncthreads();
        // write V regs -> Vt (transposed)
        #pragma unroll
        for (int it = 0; it < 4; it++) {
            int d0 = dg * 16 + it * 4;
            uint2 u = vr[it];
            Vt[vb + (d0 + 0) * 32] = (u16)(u.x & 0xffffu);
            Vt[vb + (d0 + 1) * 32] = (u16)(u.x >> 16);
            Vt[vb + (d0 + 2) * 32] = (u16)(u.y & 0xffffu);
            Vt[vb + (d0 + 3) * 32] = (u16)(u.y >> 16);
        }

        f32x4 S[2][4];
        #pragma unroll
        for (int i = 0; i < 2; i++)
            #pragma unroll
            for (int j = 0; j < 4; j++)
                S[i][j] = (f32x4){0.f, 0.f, 0.f, 0.f};
        __builtin_amdgcn_s_setprio(1);
        #pragma unroll
        for (int kc = 0; kc < 2; kc++) {
            short8 aq[2], bk[4];
            #pragma unroll
            for (int i = 0; i < 2; i++)
                aq[i] = *(const short8*)&Qs[kc * 4096 + (wave * 32 + i * 16 + r16) * 32 + quad * 8];
            #pragma unroll
            for (int j = 0; j < 4; j++)
                bk[j] = *(const short8*)&Ks[kc * 2048 + (j * 16 + r16) * 32 + quad * 8];
            #pragma unroll
            for (int i = 0; i < 2; i++)
                #pragma unroll
                for (int j = 0; j < 4; j++)
                    S[i][j] = __builtin_amdgcn_mfma_f32_16x16x32_bf16(
                        aq[i], bk[j], S[i][j], 0, 0, 0);
        }
        __builtin_amdgcn_s_setprio(0);

        #pragma unroll
        for (int i = 0; i < 2; i++) {
            #pragma unroll
            for (int j = 0; j < 4; j++) {
                const int col = j * 16 + r16;
                const int pb = (col >> 5) * 4096 + (col & 31);
                #pragma unroll
                for (int r = 0; r < 4; r++) {
                    float p = __builtin_amdgcn_exp2f(S[i][j][r] * SC);
                    lpart[i][r] += p;
                    const int row = wave * 32 + i * 16 + quad * 4 + r;
                    Ps[pb + row * 32] = f2bf_fast(p);
                }
            }
        }

        // (b) all waves past QK^T (Ks dead) and Ps fully written
        __syncthreads();

        if (kt < 15) {
            const u16* kbase = qkv + (size_t)(b * 1024 + (kt + 1) * 64) * RS + 768 + h * 64;
            #pragma unroll
            for (int c = 0; c < 2; c++) {
                int idx = wave * 2 + c;
                int kc = idx >> 2, rg = idx & 3;
                int row = rg * 16 + (lane >> 2);
                gload16(kbase + (size_t)row * RS + kc * 32 + (lane & 3) * 8,
                        &Ks[kc * 2048 + rg * 512]);
            }
            const u16* vbase = qkv + (size_t)(b * 1024 + (kt + 1) * 64) * RS + 1536 + h * 64;
            #pragma unroll
            for (int it = 0; it < 4; it++) {
                int d0 = dg * 16 + it * 4;
                vr[it] = *(const uint2*)(vbase + (size_t)kp * RS + d0);
            }
        }

        __builtin_amdgcn_s_setprio(1);
        #pragma unroll
        for (int kc = 0; kc < 2; kc++) {
            short8 ap[2], bv[4];
            #pragma unroll
            for (int i = 0; i < 2; i++)
                ap[i] = *(const short8*)&Ps[kc * 4096 + (wave * 32 + i * 16 + r16) * 32 + quad * 8];
            #pragma unroll
            for (int j = 0; j < 4; j++)
                bv[j] = *(const short8*)&Vt[kc * 2048 + (j * 16 + r16) * 32 + quad * 8];
            #pragma unroll
            for (int i = 0; i < 2; i++)
                #pragma unroll
                for (int j = 0; j < 4; j++)
                    O[i][j] = __builtin_amdgcn_mfma_f32_16x16x32_bf16(
                        ap[i], bv[j], O[i][j], 0, 0, 0);
        }
        __builtin_amdgcn_s_setprio(0);
    }

    // epilogue: wave-private repack through Ps (dead), coalesced 16B stores
    const int row = lane >> 2, seg = (lane & 3) * 16;
    #pragma unroll
    for (int i = 0; i < 2; i++) {
        float linv[4];
        #pragma unroll
        for (int r = 0; r < 4; r++) {
            float l = lpart[i][r];
            l += __shfl_xor(l, 1);
            l += __shfl_xor(l, 2);
            l += __shfl_xor(l, 4);
            l += __shfl_xor(l, 8);
            linv[r] = 1.0f / l;
        }
        u16* myl = &Ps[wave * 2048 + i * 1024];   // 16 rows x 64 cols
        #pragma unroll
        for (int j = 0; j < 4; j++)
            #pragma unroll
            for (int r = 0; r < 4; r++)
                myl[(quad * 4 + r) * 64 + j * 16 + r16] = f2bf(O[i][j][r] * linv[r]);
        const int token = tok0 + wave * 32 + i * 16 + row;
        const size_t oidx = (size_t)token * 768 + h * 64 + seg;
        *(ushort8v*)(out + oidx)     = *(const ushort8v*)&myl[row * 64 + seg];
        *(ushort8v*)(out + oidx + 8) = *(const ushort8v*)&myl[row * 64 + seg + 8];
    }
}

// ---------------------------------------------------------------------------
extern "C" void kernel_launch(void* const* d_in, const int* in_sizes, int n_in,
                              void* d_out, int out_size, void* d_ws, size_t ws_size,
                              hipStream_t stream)
{
    (void)in_sizes; (void)n_in; (void)out_size; (void)ws_size;
    const float* x        = (const float*)d_in[0];
    const float* ln1_g    = (const float*)d_in[1];
    const float* ln1_b    = (const float*)d_in[2];
    const float* qkv_w    = (const float*)d_in[3];
    const float* qkv_b    = (const float*)d_in[4];
    const float* proj_w   = (const float*)d_in[5];
    const float* proj_b   = (const float*)d_in[6];
    const float* c_qkv_w  = (const float*)d_in[7];
    const float* c_qkv_b  = (const float*)d_in[8];
    const float* c_proj_w = (const float*)d_in[9];
    const float* c_proj_b = (const float*)d_in[10];
    const float* cp_fc1_w = (const float*)d_in[11];
    const float* cp_fc1_b = (const float*)d_in[12];
    const float* cp_fc2_w = (const float*)d_in[13];
    const float* cp_fc2_b = (const float*)d_in[14];
    const float* P        = (const float*)d_in[15];
    const float* ln2_g    = (const float*)d_in[16];
    const float* ln2_b    = (const float*)d_in[17];
    const float* fc1_w    = (const float*)d_in[18];
    const float* fc1_b    = (const float*)d_in[19];
    const float* fc2_w    = (const float*)d_in[20];
    const float* fc2_b    = (const float*)d_in[21];

    float* out_x    = (float*)d_out;               // (8,1024,768) fp32
    float* out_dmap = out_x + 6291456;             // (8,1024,64)  fp32

    // ws layout (u16 element units)
    u16* us    = (u16*)d_ws;
    u16* n1n2  = us;                         //  6291456  n1 -> zin -> n2
    u16* bigA  = us + 6291456;               // 25165824  qkv/qkv2 ; h(3072)
    u16* ao    = bigA + 18874368;            //  6291456  attn out (tail)
    u16* y     = us + 31457280;              //  6291456
    float* xs  = (float*)(us + 37748736);    //  6291456 fp32
    u16* dmapb = us + 50331648;              //   524288
    u16* cph   = us + 50855936;              //   524288
    u16* Pn    = us + 51380224;              //    49152
    float* invn = (float*)(us + 51429376);   //  8192 fp32
    u16* ci    = us + 51445760;              //  canonical bf16 weights

    u16* w_qkv   = ci;                  // 1769472
    u16* w_proj  = ci + 1769472;        // 589824
    u16* w_cqkv  = ci + 2359296;        // 1769472
    u16* w_cproj = ci + 4128768;        // 589824
    u16* w_cpf1  = ci + 4718592;        // 4096
    u16* w_cpf2  = ci + 4722688;        // 49152
    u16* w_fc1   = ci + 4771840;        // 2359296
    u16* w_fc2   = ci + 7131136;        // 2359296

    // 0. canonicalize weight matrices fp32 -> bf16 (single fused launch)
    {
        ConvArgs a;
        const float* wsrc[8] = { qkv_w, proj_w, c_qkv_w, c_proj_w,
                                 cp_fc1_w, cp_fc2_w, fc1_w, fc2_w };
        u16* wdst[8] = { w_qkv, w_proj, w_cqkv, w_cproj,
                         w_cpf1, w_cpf2, w_fc1, w_fc2 };
        const int wn[8] = { 1769472, 589824, 1769472, 589824,
                            4096, 49152, 2359296, 2359296 };
        int cum = 0;
        for (int i = 0; i < 8; i++) {
            a.src[i] = wsrc[i]; a.dst[i] = wdst[i]; a.n[i] = wn[i];
            a.nblk[i] = cum;
            cum += (wn[i] / 4 + 255) / 256;
        }
        a.nblk[8] = cum;
        conv_all_k<<<cum, 256, 0, stream>>>(a);
    }

    // 1. normalize P rows
    pn_k<<<64, 256, 0, stream>>>(P, Pn);
    // 2. n1 = LN(x), invn = 1/||n1||
    ln_k<true><<<8192, 256, 0, stream>>>(x, ln1_g, ln1_b, n1n2, invn);
    // 3. qkv = n1 @ qkv_w^T + qkv_b   (256^2 8-wave kernel)
    gemm256<F_BIAS | F_OUTB>
        <<<dim3(9, 32), 512, 0, stream>>>(n1n2, w_qkv, qkv_b, bigA,
                                          8192, 2304, 768);
    // 4. attention 1
    attn_mfma<<<dim3(8, 96), 256, 0, stream>>>(bigA, ao);
    // 5. y = ao @ proj_w^T + proj_b
    gemm_mfma<F_BIAS | F_OUTB>
        <<<dim3(6, 64), 256, 0, stream>>>(ao, w_proj, proj_b, nullptr, nullptr,
                                          y, nullptr, 8192, 768, 768);
    // 6. dmap = (n1 @ Pn^T) * invn  -> dmapb bf16 + out_dmap fp32
    gemm_k<64, 64, F_ROWSCALE | F_OUTB | F_OUTF>
        <<<dim3(1, 128), 256, 0, stream>>>(n1n2, Pn, nullptr, invn, nullptr,
                                           nullptr, dmapb, out_dmap, 8192, 64, 768);
    // 7. cph = gelu(dmap @ cp_fc1_w^T + b)
    gemm_k<64, 64, F_BIAS | F_GELU | F_OUTB>
        <<<dim3(1, 128), 256, 0, stream>>>(dmapb, w_cpf1, cp_fc1_b, nullptr,
                                           nullptr, nullptr, cph, nullptr, 8192, 64, 64);
    // 8. zin = cph @ cp_fc2_w^T + b   (zin aliases n1n2)
    gemm_mfma<F_BIAS | F_OUTB>
        <<<dim3(6, 64), 256, 0, stream>>>(cph, w_cpf2, cp_fc2_b, nullptr, nullptr,
                                          n1n2, nullptr, 8192, 768, 64);
    // 9. qkv2 = zin @ c_qkv_w^T + b   (256^2 8-wave kernel)
    gemm256<F_BIAS | F_OUTB>
        <<<dim3(9, 32), 512, 0, stream>>>(n1n2, w_cqkv, c_qkv_b, bigA,
                                          8192, 2304, 768);
    // 10. attention 2
    attn_mfma<<<dim3(8, 96), 256, 0, stream>>>(bigA, ao);
    // 11. xs = ao2 @ c_proj_w^T + b + y + x   (y bf16, x fp32) -> fp32
    gemm_mfma<F_BIAS | F_RES1 | F_RESF | F_OUTF>
        <<<dim3(6, 64), 256, 0, stream>>>(ao, w_cproj, c_proj_b, y, x,
                                          nullptr, xs, 8192, 768, 768);
    // 12. n2 = LN(xs)
    ln_k<false><<<8192, 256, 0, stream>>>(xs, ln2_g, ln2_b, n1n2, nullptr);
    // 13. h = gelu(n2 @ fc1_w^T + b)   (256^2 8-wave kernel)
    gemm256<F_BIAS | F_GELU | F_OUTB>
        <<<dim3(12, 32), 512, 0, stream>>>(n1n2, w_fc1, fc1_b, bigA,
                                           8192, 3072, 768);
    // 14. out = h @ fc2_w^T + b + xs  -> fp32 d_out
    gemm_mfma<F_BIAS | F_RESF | F_OUTF>
        <<<dim3(6, 64), 256, 0, stream>>>(bigA, w_fc2, fc2_b, nullptr, xs,
                                          nullptr, out_x, 8192, 768, 3072);
}

// Round 7
// 579.847 us; speedup vs baseline: 1.0145x; 1.0145x over previous
//
#include <hip/hip_runtime.h>

// ---------------------------------------------------------------------------
// Transformer block w/ SimilarityMaps branch. fp32 inputs/outputs; weights
// canonicalized to bf16; GEMMs + attention on MFMA (16x16x32 bf16).
// B=8 N=1024 C=768 H=12 hd=64 K_PARTS=64 HID=3072. Tokens M = 8192.
// Round 15: gemm256 rebuilt as a 4-phase-per-K-tile interleaved schedule
//   (T3+T4). R6 proved the coarse 2-phase 256^2 regresses (18% MfmaUtil,
//   1 block/CU, LDS-read burst serializes). Phases interleave ds_read /
//   half-tile staging / MFMA with per-phase barriers + setprio; staging
//   always targets the other double-buffer (race-free); one vmcnt(0) per
//   K-tile with >=1 phase of load age.
// ---------------------------------------------------------------------------

typedef unsigned short u16;
typedef unsigned int   u32;
typedef __attribute__((ext_vector_type(8))) short short8;       // bf16 x8 frag
typedef __attribute__((ext_vector_type(8))) unsigned short ushort8v;
typedef __attribute__((ext_vector_type(4))) float f32x4;        // MFMA accum

#define F_GELU     1
#define F_ROWSCALE 2
#define F_RES1     4    // bf16 residual (res1)
#define F_RESF     8    // fp32 residual (resf)
#define F_OUTB     16   // write bf16 to out
#define F_OUTF     32   // write fp32 to outf
#define F_BIAS     64   // fp32 bias

__device__ __forceinline__ float bf2f(u32 b) { return __uint_as_float(b << 16); }
__device__ __forceinline__ u16 f2bf(float f) {
    u32 u = __float_as_uint(f);
    u32 r = u + 0x7fffu + ((u >> 16) & 1u);   // RNE
    return (u16)(r >> 16);
}
__device__ __forceinline__ u16 f2bf_fast(float f) {
    return (u16)((__float_as_uint(f) + 0x8000u) >> 16);
}
__device__ __forceinline__ float gelu_exact(float v) {
    return 0.5f * v * (1.0f + erff(v * 0.70710678118654752440f));
}
// tanh-form GELU (max abs dev from exact ~3e-3; cheap: 1 transcendental)
__device__ __forceinline__ float gelu_fast(float x) {
    float u = 0.79788456080286535588f * (x + 0.044715f * x * x * x);
    float e = __builtin_amdgcn_exp2f(u * 2.88539008177792681472f);  // exp(2u)
    float t = 1.0f - 2.0f / (e + 1.0f);
    return 0.5f * x * (1.0f + t);
}

// async global->LDS, 16 B per lane; lds base must be wave-uniform
__device__ __forceinline__ void gload16(const u16* g, u16* l) {
    __builtin_amdgcn_global_load_lds(
        (const __attribute__((address_space(1))) u32*)g,
        (__attribute__((address_space(3))) u32*)l, 16, 0, 0);
}

// ---------------- fp32 -> bf16 weight canonicalization (all 8, fused) ------
struct ConvArgs {
    const float* src[8];
    u16*         dst[8];
    int          nblk[9];   // cumulative block offsets
    int          n[8];
};

__global__ __launch_bounds__(256)
void conv_all_k(ConvArgs a)
{
    const int b = blockIdx.x;
    int i = 0;
    #pragma unroll
    for (int j = 0; j < 7; j++) if (b >= a.nblk[j + 1]) i = j + 1;
    const int base = (b - a.nblk[i]) * 1024 + threadIdx.x * 4;
    if (base >= a.n[i]) return;
    float4 v = *(const float4*)(a.src[i] + base);
    ushort4 o;
    o.x = f2bf(v.x); o.y = f2bf(v.y); o.z = f2bf(v.z); o.w = f2bf(v.w);
    *(ushort4*)(a.dst[i] + base) = o;
}

__device__ __forceinline__ float block_sum(float v, float* red) {
    #pragma unroll
    for (int off = 32; off > 0; off >>= 1) v += __shfl_down(v, off);
    __syncthreads();
    if ((threadIdx.x & 63) == 0) red[threadIdx.x >> 6] = v;
    __syncthreads();
    return red[0] + red[1] + red[2] + red[3];
}

// ---------------- LayerNorm over 768 (fp32 in, bf16 out), opt 1/||y|| ------
template<bool NORM>
__global__ __launch_bounds__(256)
void ln_k(const float* __restrict__ xin, const float* __restrict__ g,
          const float* __restrict__ bta, u16* __restrict__ out,
          float* __restrict__ invnorm)
{
    __shared__ float red[4];
    const int row = blockIdx.x, t = threadIdx.x;
    float v[3];
    #pragma unroll
    for (int i = 0; i < 3; i++)
        v[i] = xin[(size_t)row * 768 + t + i * 256];
    float tot = block_sum(v[0] + v[1] + v[2], red);
    float mu  = tot * (1.0f / 768.0f);
    float d0 = v[0] - mu, d1 = v[1] - mu, d2 = v[2] - mu;
    float tot2 = block_sum(d0 * d0 + d1 * d1 + d2 * d2, red);
    float rstd = rsqrtf(tot2 * (1.0f / 768.0f) + 1e-5f);
    float ss = 0.0f;
    #pragma unroll
    for (int i = 0; i < 3; i++) {
        int c = t + i * 256;
        float yy = (v[i] - mu) * rstd * g[c] + bta[c];
        out[(size_t)row * 768 + c] = f2bf(yy);
        ss += yy * yy;
    }
    if constexpr (NORM) {
        float tot3 = block_sum(ss, red);
        if (t == 0) invnorm[row] = rsqrtf(tot3);
    }
}

// ---------------- P row-normalize: Pn = bf16(P / ||P_row||) ----------------
__global__ __launch_bounds__(256)
void pn_k(const float* __restrict__ P, u16* __restrict__ Pn)
{
    __shared__ float red[4];
    const int row = blockIdx.x, t = threadIdx.x;
    float v[3];
    #pragma unroll
    for (int i = 0; i < 3; i++)
        v[i] = P[(size_t)row * 768 + t + i * 256];
    float tot = block_sum(v[0]*v[0] + v[1]*v[1] + v[2]*v[2], red);
    float inv = rsqrtf(tot);
    #pragma unroll
    for (int i = 0; i < 3; i++)
        Pn[(size_t)row * 768 + t + i * 256] = f2bf(v[i] * inv);
}

// ---------------- MFMA GEMM 256x256, 4-phase interleave --------------------
// 512 threads = 8 waves (2M x 4N), wave owns 128x64 (acc[8][4]). BK=64,
// double-buffered LDS 128 KB. Per K-tile, 4 phases; phase q:
//   { ds_read A-quadrant (rows 2q,2q+1; 4 b128) [+ B all 8 b128 at q=0,
//     held in regs] ; stage half-tile(s) of tile kt+1 into the OTHER dbuf ;
//     [q==3: vmcnt(0) -- tile kt+1 fully landed] ; barrier ;
//     setprio(1) 16 MFMA setprio(0) ; barrier }
// LDS XOR swizzle c' = c ^ (row&7), both sides (stage pre-swizzles global
// source; reads apply same XOR). Measured 0 bank conflicts (R6).
// Requires M%256==0, N%256==0, K%64==0, gridDim.y%8==0.
template<int FLAGS>
__global__ __launch_bounds__(512, 2)
void gemm256(const u16* __restrict__ A, const u16* __restrict__ W,
             const float* __restrict__ bias, u16* __restrict__ out,
             int M, int N, int K)
{
    __shared__ u16 As[2][16384];   // [dbuf][256 rows][64 cols]
    __shared__ u16 Bs[2][16384];
    const int t = threadIdx.x;
    const int wave = t >> 6, lane = t & 63;
    const int quad = lane >> 4, r16 = lane & 15;
    const int wr = wave >> 2, wc = wave & 3;   // wave position: 2M x 4N

    // XCD-chunked block order (col-major within chunk for W reuse)
    const int nbx = gridDim.x, nby = gridDim.y;
    const int orig = blockIdx.x + blockIdx.y * nbx;
    const int Rc   = nby >> 3;                 // tile-rows per XCD
    const int xcd  = orig & 7, loc = orig >> 3;
    const int m0 = (xcd * Rc + (loc % Rc)) * 256;
    const int n0 = (loc / Rc) * 256;
    const int NT = K >> 6;

    f32x4 acc[8][4];
    #pragma unroll
    for (int i = 0; i < 8; i++)
        #pragma unroll
        for (int j = 0; j < 4; j++)
            acc[i][j] = (f32x4){0.f, 0.f, 0.f, 0.f};

    // staging: half-tile = 128x64 = 2 issues x 64 rows; wave covers 8 rows
    // per issue; lane: row = wave*8 + (lane>>3), chunk c = lane&7.
    // global col16 pre-swizzled: c ^ (row&7) = c ^ ((lane>>3)&7).
    const int srow = wave * 8 + (lane >> 3);
    const int scol = ((lane & 7) ^ ((lane >> 3) & 7)) * 8;

    const u16* Abase = A + (size_t)m0 * K;
    const u16* Wbase = W + (size_t)n0 * K;

    // stage half h (0,1 = A rows 0-127/128-255; 2,3 = B) of k-tile kt -> buf e
    auto stage_half = [&](int h, int kt, int e) {
        const int k0 = kt * 64;
        const u16* g = (h < 2) ? (Abase + (size_t)((h & 1) * 128) * K)
                               : (Wbase + (size_t)((h & 1) * 128) * K);
        u16* l = (h < 2) ? &As[e][(h & 1) * 8192] : &Bs[e][(h & 1) * 8192];
        #pragma unroll
        for (int i = 0; i < 2; i++)
            gload16(g + (size_t)(i * 64 + srow) * K + k0 + scol,
                    l + i * 4096 + wave * 512);
    };

    // prologue: stage tile 0 into dbuf 0, drain, sync
    #pragma unroll
    for (int h = 0; h < 4; h++) stage_half(h, 0, 0);
    asm volatile("s_waitcnt vmcnt(0)" ::: "memory");
    __syncthreads();

    short8 bfr[2][4];   // B fragments, held across the 4 phases of a K-tile
    for (int kt = 0; kt < NT; kt++) {
        const int d = kt & 1, e = d ^ 1;
        const bool pf = (kt + 1 < NT);
        #pragma unroll
        for (int q = 0; q < 4; q++) {
            // ds_read: A quadrant (rows 2q, 2q+1), both K32 halves
            short8 af[2][2];
            #pragma unroll
            for (int ks = 0; ks < 2; ks++)
                #pragma unroll
                for (int ii = 0; ii < 2; ii++) {
                    const int ar = wr * 128 + (q * 2 + ii) * 16 + r16;
                    af[ks][ii] = *(const short8*)
                        &As[d][ar * 64 + (((ks * 4 + quad) ^ (ar & 7)) * 8)];
                }
            if (q == 0) {
                #pragma unroll
                for (int ks = 0; ks < 2; ks++)
                    #pragma unroll
                    for (int j = 0; j < 4; j++) {
                        const int br = wc * 64 + j * 16 + r16;
                        bfr[ks][j] = *(const short8*)
                            &Bs[d][br * 64 + (((ks * 4 + quad) ^ (br & 7)) * 8)];
                    }
            }
            // stage tile kt+1 into the other dbuf (never the one being read)
            // halves at phases 0(x2),1,2 so the youngest load is >=1 phase
            // old at the q==3 drain.
            if (pf) {
                if (q == 0) { stage_half(0, kt + 1, e); stage_half(1, kt + 1, e); }
                else if (q == 1) stage_half(2, kt + 1, e);
                else if (q == 2) stage_half(3, kt + 1, e);
            }
            if (q == 3)
                asm volatile("s_waitcnt vmcnt(0)" ::: "memory");
            asm volatile("s_barrier" ::: "memory");
            __builtin_amdgcn_s_setprio(1);
            #pragma unroll
            for (int ks = 0; ks < 2; ks++)
                #pragma unroll
                for (int ii = 0; ii < 2; ii++)
                    #pragma unroll
                    for (int j = 0; j < 4; j++)
                        acc[q * 2 + ii][j] = __builtin_amdgcn_mfma_f32_16x16x32_bf16(
                            af[ks][ii], bfr[ks][j], acc[q * 2 + ii][j], 0, 0, 0);
            __builtin_amdgcn_s_setprio(0);
            asm volatile("s_barrier" ::: "memory");
        }
    }

    // ---- epilogue: wave-private fp32 repack (stride 68, conflict-free) ----
    // (final phase barrier => all waves done reading LDS)
    float* myl = (float*)&As[0][0] + wave * 1088;   // 16 rows x 68 cols fp32
    float bj[4];
    #pragma unroll
    for (int j = 0; j < 4; j++) {
        if constexpr (FLAGS & F_BIAS) bj[j] = bias[n0 + wc * 64 + j * 16 + r16];
        else bj[j] = 0.0f;
    }
    const int row = lane >> 2, seg = (lane & 3) * 16;

    #pragma unroll
    for (int i = 0; i < 8; i++) {
        #pragma unroll
        for (int j = 0; j < 4; j++)
            #pragma unroll
            for (int r = 0; r < 4; r++) {
                float v = acc[i][j][r] + bj[j];
                if constexpr (FLAGS & F_GELU) v = gelu_fast(v);
                myl[(quad * 4 + r) * 68 + j * 16 + r16] = v;
            }
        float v[16];
        #pragma unroll
        for (int k4 = 0; k4 < 4; k4++) {
            float4 f = *(const float4*)&myl[row * 68 + seg + k4 * 4];
            v[k4 * 4 + 0] = f.x; v[k4 * 4 + 1] = f.y;
            v[k4 * 4 + 2] = f.z; v[k4 * 4 + 3] = f.w;
        }
        const int m = m0 + wr * 128 + i * 16 + row;
        const size_t idx = (size_t)m * N + n0 + wc * 64 + seg;
        ushort8v o0, o1;
        #pragma unroll
        for (int k = 0; k < 8; k++) { o0[k] = f2bf(v[k]); o1[k] = f2bf(v[k + 8]); }
        *(ushort8v*)(out + idx) = o0;
        *(ushort8v*)(out + idx + 8) = o1;
    }
}

// ---------------- MFMA GEMM: C[M,N] = A[M,K] * W[N,K]^T (+epilogue) --------
// 128x128 tile, BK=32; 4 waves, each a 64x64 sub-tile. Triple-buffered LDS,
// 2-deep prefetch, one barrier per K-iter. XCD-chunked block order with
// intra-chunk col-grouping (G=6). Used for the N=768 / K<=64 GEMMs.
template<int FLAGS>
__global__ __launch_bounds__(256)
void gemm_mfma(const u16* __restrict__ A, const u16* __restrict__ W,
               const float* __restrict__ bias,
               const u16* __restrict__ res1, const float* __restrict__ resf,
               u16* __restrict__ out, float* __restrict__ outf,
               int M, int N, int K)
{
    __shared__ u16 smem[3][8192];        // [buf][ As 4096 | Bs 4096 ] = 48 KB
    const int t = threadIdx.x;
    const int wave = t >> 6, lane = t & 63;
    const int nbx  = gridDim.x;
    const int orig = blockIdx.x + blockIdx.y * nbx;
    const int cpx  = (nbx * gridDim.y) >> 3;   // wgs per XCD chunk
    const int xcd  = orig & 7, loc = orig >> 3;
    const int Rc   = cpx / nbx;                // rows per chunk (8 here)
    const int gsz  = 6 * Rc;                   // wgs per col-group
    const int grp  = loc / gsz;
    const int rem  = loc - grp * gsz;
    const int ccol = grp * 6 + rem % 6;
    const int crow = xcd * Rc + rem / 6;
    const int m0 = crow * 128, n0 = ccol * 128;
    const int Wm = (wave >> 1) * 64, Wn = (wave & 1) * 64;
    const int rr = lane >> 2, cc = (lane & 3) * 8;
    const int quad = lane >> 4, r16 = lane & 15;
    const int NK = K >> 5;

    f32x4 acc[4][4];
    #pragma unroll
    for (int i = 0; i < 4; i++)
        #pragma unroll
        for (int j = 0; j < 4; j++)
            acc[i][j] = (f32x4){0.f, 0.f, 0.f, 0.f};

    // prologue: stage k-tiles 0 and 1 into bufs 0,1 (order matters for vmcnt)
    #pragma unroll
    for (int c = 0; c < 2; c++) {
        const int chunk = wave * 2 + c;
        const int row = chunk * 16 + rr;
        gload16(A + (size_t)(m0 + row) * K + cc, &smem[0][chunk * 512]);
        gload16(W + (size_t)(n0 + row) * K + cc, &smem[0][4096 + chunk * 512]);
    }
    if (NK > 1) {
        #pragma unroll
        for (int c = 0; c < 2; c++) {
            const int chunk = wave * 2 + c;
            const int row = chunk * 16 + rr;
            gload16(A + (size_t)(m0 + row) * K + 32 + cc, &smem[1][chunk * 512]);
            gload16(W + (size_t)(n0 + row) * K + 32 + cc, &smem[1][4096 + chunk * 512]);
        }
    }

    for (int kt = 0; kt < NK; kt++) {
        const int cur = kt % 3;
        if (kt + 1 < NK)
            asm volatile("s_waitcnt vmcnt(4)\n\ts_barrier" ::: "memory");
        else
            asm volatile("s_waitcnt vmcnt(0)\n\ts_barrier" ::: "memory");
        if (kt + 2 < NK) {
            const int k0 = (kt + 2) * 32;
            const int nb = (kt + 2) % 3;
            #pragma unroll
            for (int c = 0; c < 2; c++) {
                const int chunk = wave * 2 + c;
                const int row = chunk * 16 + rr;
                gload16(A + (size_t)(m0 + row) * K + k0 + cc,
                        &smem[nb][chunk * 512]);
                gload16(W + (size_t)(n0 + row) * K + k0 + cc,
                        &smem[nb][4096 + chunk * 512]);
            }
        }
        short8 af[4], bfr[4];
        #pragma unroll
        for (int i = 0; i < 4; i++) {
            af[i]  = *(const short8*)&smem[cur][(Wm + i * 16 + r16) * 32 + quad * 8];
            bfr[i] = *(const short8*)&smem[cur][4096 + (Wn + i * 16 + r16) * 32 + quad * 8];
        }
        #pragma unroll
        for (int i = 0; i < 4; i++)
            #pragma unroll
            for (int j = 0; j < 4; j++)
                acc[i][j] = __builtin_amdgcn_mfma_f32_16x16x32_bf16(
                    af[i], bfr[j], acc[i][j], 0, 0, 0);
    }
    __syncthreads();

    // ---- epilogue: wave-private fp32 repack (no cross-wave sync) ----
    float* myl = (float*)&smem[0][0] + wave * 1088;   // 16 rows x 68 cols fp32
    float bj[4];
    #pragma unroll
    for (int j = 0; j < 4; j++) {
        if constexpr (FLAGS & F_BIAS) bj[j] = bias[n0 + Wn + j * 16 + r16];
        else bj[j] = 0.0f;
    }
    const int row = lane >> 2, seg = (lane & 3) * 16;

    #pragma unroll
    for (int i = 0; i < 4; i++) {
        #pragma unroll
        for (int j = 0; j < 4; j++)
            #pragma unroll
            for (int r = 0; r < 4; r++) {
                float v = acc[i][j][r] + bj[j];
                if constexpr (FLAGS & F_GELU) v = gelu_fast(v);
                myl[(quad * 4 + r) * 68 + j * 16 + r16] = v;
            }
        float v[16];
        #pragma unroll
        for (int k4 = 0; k4 < 4; k4++) {
            float4 f = *(const float4*)&myl[row * 68 + seg + k4 * 4];
            v[k4 * 4 + 0] = f.x; v[k4 * 4 + 1] = f.y;
            v[k4 * 4 + 2] = f.z; v[k4 * 4 + 3] = f.w;
        }
        const int m = m0 + Wm + i * 16 + row;
        const size_t idx = (size_t)m * N + n0 + Wn + seg;
        if constexpr (FLAGS & F_RES1) {
            ushort8v r0 = *(const ushort8v*)(res1 + idx);
            ushort8v r1 = *(const ushort8v*)(res1 + idx + 8);
            #pragma unroll
            for (int k = 0; k < 8; k++) { v[k] += bf2f(r0[k]); v[k + 8] += bf2f(r1[k]); }
        }
        if constexpr (FLAGS & F_RESF) {
            #pragma unroll
            for (int k4 = 0; k4 < 4; k4++) {
                float4 f = *(const float4*)(resf + idx + k4 * 4);
                v[k4 * 4 + 0] += f.x; v[k4 * 4 + 1] += f.y;
                v[k4 * 4 + 2] += f.z; v[k4 * 4 + 3] += f.w;
            }
        }
        if constexpr (FLAGS & F_OUTB) {
            ushort8v o0, o1;
            #pragma unroll
            for (int k = 0; k < 8; k++) { o0[k] = f2bf(v[k]); o1[k] = f2bf(v[k + 8]); }
            *(ushort8v*)(out + idx) = o0;
            *(ushort8v*)(out + idx + 8) = o1;
        }
        if constexpr (FLAGS & F_OUTF) {
            #pragma unroll
            for (int k4 = 0; k4 < 4; k4++) {
                float4 f = {v[k4 * 4 + 0], v[k4 * 4 + 1], v[k4 * 4 + 2], v[k4 * 4 + 3]};
                *(float4*)(outf + idx + k4 * 4) = f;
            }
        }
    }
}

// ---------------- small fp32 GEMM (64x64 tiles) for the K-parts branch -----
template<int BM, int BN, int FLAGS>
__global__ __launch_bounds__(256)
void gemm_k(const u16* __restrict__ A, const u16* __restrict__ W,
            const float* __restrict__ bias, const float* __restrict__ rowscale,
            const u16* __restrict__ res1, const float* __restrict__ resf,
            u16* __restrict__ out, float* __restrict__ outf,
            int M, int N, int K)
{
    constexpr int RM = BM / 16, RN = BN / 16;
    __shared__ float Asm[16][BM + 4];
    __shared__ float Wsm[16][BN + 4];
    const int t  = threadIdx.x;
    const int tx = t & 15, ty = t >> 4;
    const int m0 = blockIdx.y * BM, n0 = blockIdx.x * BN;

    float acc[RM][RN];
    #pragma unroll
    for (int i = 0; i < RM; i++)
        #pragma unroll
        for (int j = 0; j < RN; j++) acc[i][j] = 0.0f;

    for (int k0 = 0; k0 < K; k0 += 16) {
        #pragma unroll
        for (int i = 0; i < BM / 64; i++) {
            int f = t + i * 256, r = f >> 2, c4 = (f & 3) << 2;
            uint2 u = *(const uint2*)(A + (size_t)(m0 + r) * K + k0 + c4);
            Asm[c4 + 0][r] = bf2f(u.x & 0xffffu);
            Asm[c4 + 1][r] = bf2f(u.x >> 16);
            Asm[c4 + 2][r] = bf2f(u.y & 0xffffu);
            Asm[c4 + 3][r] = bf2f(u.y >> 16);
        }
        #pragma unroll
        for (int i = 0; i < BN / 64; i++) {
            int f = t + i * 256, r = f >> 2, c4 = (f & 3) << 2;
            uint2 u = *(const uint2*)(W + (size_t)(n0 + r) * K + k0 + c4);
            Wsm[c4 + 0][r] = bf2f(u.x & 0xffffu);
            Wsm[c4 + 1][r] = bf2f(u.x >> 16);
            Wsm[c4 + 2][r] = bf2f(u.y & 0xffffu);
            Wsm[c4 + 3][r] = bf2f(u.y >> 16);
        }
        __syncthreads();
        #pragma unroll
        for (int k = 0; k < 16; k++) {
            float a[RM], w[RN];
            #pragma unroll
            for (int ii = 0; ii < RM; ii += 4) {
                float4 v = *(const float4*)&Asm[k][ty * RM + ii];
                a[ii] = v.x; a[ii + 1] = v.y; a[ii + 2] = v.z; a[ii + 3] = v.w;
            }
            #pragma unroll
            for (int jj = 0; jj < RN; jj += 4) {
                float4 v = *(const float4*)&Wsm[k][tx * RN + jj];
                w[jj] = v.x; w[jj + 1] = v.y; w[jj + 2] = v.z; w[jj + 3] = v.w;
            }
            #pragma unroll
            for (int i = 0; i < RM; i++)
                #pragma unroll
                for (int j = 0; j < RN; j++)
                    acc[i][j] = fmaf(a[i], w[j], acc[i][j]);
        }
        __syncthreads();
    }

    #pragma unroll
    for (int i = 0; i < RM; i++) {
        const int m = m0 + ty * RM + i;
        float rs = 1.0f;
        if constexpr (FLAGS & F_ROWSCALE) rs = rowscale[m];
        #pragma unroll
        for (int jj = 0; jj < RN; jj += 4) {
            const int n = n0 + tx * RN + jj;
            const size_t idx = (size_t)m * N + n;
            float b4[4] = {0.f, 0.f, 0.f, 0.f};
            if constexpr (FLAGS & F_BIAS) {
                float4 bvv = *(const float4*)(bias + n);
                b4[0] = bvv.x; b4[1] = bvv.y; b4[2] = bvv.z; b4[3] = bvv.w;
            }
            float e[4];
            #pragma unroll
            for (int j = 0; j < 4; j++) {
                float v = acc[i][jj + j];
                if constexpr (FLAGS & F_BIAS) v += b4[j];
                if constexpr (FLAGS & F_GELU) v = gelu_exact(v);
                if constexpr (FLAGS & F_ROWSCALE) v *= rs;
                e[j] = v;
            }
            if constexpr (FLAGS & F_OUTB) {
                ushort4 o4;
                o4.x = f2bf(e[0]); o4.y = f2bf(e[1]);
                o4.z = f2bf(e[2]); o4.w = f2bf(e[3]);
                *(ushort4*)(out + idx) = o4;
            }
            if constexpr (FLAGS & F_OUTF) {
                float4 o4 = {e[0], e[1], e[2], e[3]};
                *(float4*)(outf + idx) = o4;
            }
        }
    }
}

// ---------------- MFMA flash attention (bf16, max-free online softmax) ----
// Staging for tile kt+1 (K-DMA + V reg loads) is issued between softmax and
// PV of tile kt, so HBM/L2 latency hides under PV + the next barrier.
__global__ __launch_bounds__(256)
void attn_mfma(const u16* __restrict__ qkv, u16* __restrict__ out)
{
    const int orig = blockIdx.x + blockIdx.y * 8;
    const int wg   = (orig & 7) * 96 + (orig >> 3);
    const int qt = wg & 7;                // 0..7  (128-row q tiles)
    const int bh = wg >> 3;               // 0..95
    const int b = bh / 12, h = bh % 12;
    __shared__ u16 Qs[2 * 128 * 32];      // 16 KB
    __shared__ u16 Ks[2 * 64 * 32];       //  8 KB
    __shared__ u16 Vt[2 * 64 * 32];       //  8 KB  (transposed: rows = d)
    __shared__ u16 Ps[2 * 128 * 32];      // 16 KB; epilogue: 4 waves x 2 x 16x64
    const int t = threadIdx.x;
    const int wave = t >> 6, lane = t & 63;
    const int quad = lane >> 4, r16 = lane & 15;
    const size_t RS = 2304;
    const int tok0 = b * 1024 + qt * 128;
    const u16* qbase = qkv + (size_t)tok0 * RS + h * 64;
    const float SC = 0.125f * 1.44269504088896340736f;   // scale * log2(e)

    #pragma unroll
    for (int c = 0; c < 4; c++) {
        int idx = wave * 4 + c;
        int kc = idx >> 3, rg = idx & 7;
        int row = rg * 16 + (lane >> 2);
        gload16(qbase + (size_t)row * RS + kc * 32 + (lane & 3) * 8,
                &Qs[kc * 4096 + rg * 512]);
    }

    f32x4 O[2][4];
    float lpart[2][4];
    #pragma unroll
    for (int i = 0; i < 2; i++)
        #pragma unroll
        for (int j = 0; j < 4; j++) {
            O[i][j] = (f32x4){0.f, 0.f, 0.f, 0.f};
            lpart[i][j & 3] = 0.0f;
        }

    // staging helpers
    const int kp = t & 63, dg = t >> 6;
    const int vb = (kp >> 5) * 2048 + (kp & 31);
    uint2 vr[4];

    // prologue: stage kt=0 (K-DMA into Ks, V into regs)
    {
        const u16* kbase = qkv + (size_t)(b * 1024) * RS + 768 + h * 64;
        #pragma unroll
        for (int c = 0; c < 2; c++) {
            int idx = wave * 2 + c;
            int kc = idx >> 2, rg = idx & 3;
            int row = rg * 16 + (lane >> 2);
            gload16(kbase + (size_t)row * RS + kc * 32 + (lane & 3) * 8,
                    &Ks[kc * 2048 + rg * 512]);
        }
        const u16* vbase = qkv + (size_t)(b * 1024) * RS + 1536 + h * 64;
        #pragma unroll
        for (int it = 0; it < 4; it++) {
            int d0 = dg * 16 + it * 4;
            vr[it] = *(const uint2*)(vbase + (size_t)kp * RS + d0);
        }
    }

    for (int kt = 0; kt < 16; kt++) {
        // (a) drains K-DMA + V loads (+ Q on first iter); gates Vt/Ps reuse
        __syncthreads();
        // write V regs -> Vt (transposed)
        #pragma unroll
        for (int it = 0; it < 4; it++) {
            int d0 = dg * 16 + it * 4;
            uint2 u = vr[it];
            Vt[vb + (d0 + 0) * 32] = (u16)(u.x & 0xffffu);
            Vt[vb + (d0 + 1) * 32] = (u16)(u.x >> 16);
            Vt[vb + (d0 + 2) * 32] = (u16)(u.y & 0xffffu);
            Vt[vb + (d0 + 3) * 32] = (u16)(u.y >> 16);
        }

        f32x4 S[2][4];
        #pragma unroll
        for (int i = 0; i < 2; i++)
            #pragma unroll
            for (int j = 0; j < 4; j++)
                S[i][j] = (f32x4){0.f, 0.f, 0.f, 0.f};
        __builtin_amdgcn_s_setprio(1);
        #pragma unroll
        for (int kc = 0; kc < 2; kc++) {
            short8 aq[2], bk[4];
            #pragma unroll
            for (int i = 0; i < 2; i++)
                aq[i] = *(const short8*)&Qs[kc * 4096 + (wave * 32 + i * 16 + r16) * 32 + quad * 8];
            #pragma unroll
            for (int j = 0; j < 4; j++)
                bk[j] = *(const short8*)&Ks[kc * 2048 + (j * 16 + r16) * 32 + quad * 8];
            #pragma unroll
            for (int i = 0; i < 2; i++)
                #pragma unroll
                for (int j = 0; j < 4; j++)
                    S[i][j] = __builtin_amdgcn_mfma_f32_16x16x32_bf16(
                        aq[i], bk[j], S[i][j], 0, 0, 0);
        }
        __builtin_amdgcn_s_setprio(0);

        #pragma unroll
        for (int i = 0; i < 2; i++) {
            #pragma unroll
            for (int j = 0; j < 4; j++) {
                const int col = j * 16 + r16;
                const int pb = (col >> 5) * 4096 + (col & 31);
                #pragma unroll
                for (int r = 0; r < 4; r++) {
                    float p = __builtin_amdgcn_exp2f(S[i][j][r] * SC);
                    lpart[i][r] += p;
                    const int row = wave * 32 + i * 16 + quad * 4 + r;
                    Ps[pb + row * 32] = f2bf_fast(p);
                }
            }
        }

        // (b) all waves past QK^T (Ks dead) and Ps fully written
        __syncthreads();

        if (kt < 15) {
            const u16* kbase = qkv + (size_t)(b * 1024 + (kt + 1) * 64) * RS + 768 + h * 64;
            #pragma unroll
            for (int c = 0; c < 2; c++) {
                int idx = wave * 2 + c;
                int kc = idx >> 2, rg = idx & 3;
                int row = rg * 16 + (lane >> 2);
                gload16(kbase + (size_t)row * RS + kc * 32 + (lane & 3) * 8,
                        &Ks[kc * 2048 + rg * 512]);
            }
            const u16* vbase = qkv + (size_t)(b * 1024 + (kt + 1) * 64) * RS + 1536 + h * 64;
            #pragma unroll
            for (int it = 0; it < 4; it++) {
                int d0 = dg * 16 + it * 4;
                vr[it] = *(const uint2*)(vbase + (size_t)kp * RS + d0);
            }
        }

        __builtin_amdgcn_s_setprio(1);
        #pragma unroll
        for (int kc = 0; kc < 2; kc++) {
            short8 ap[2], bv[4];
            #pragma unroll
            for (int i = 0; i < 2; i++)
                ap[i] = *(const short8*)&Ps[kc * 4096 + (wave * 32 + i * 16 + r16) * 32 + quad * 8];
            #pragma unroll
            for (int j = 0; j < 4; j++)
                bv[j] = *(const short8*)&Vt[kc * 2048 + (j * 16 + r16) * 32 + quad * 8];
            #pragma unroll
            for (int i = 0; i < 2; i++)
                #pragma unroll
                for (int j = 0; j < 4; j++)
                    O[i][j] = __builtin_amdgcn_mfma_f32_16x16x32_bf16(
                        ap[i], bv[j], O[i][j], 0, 0, 0);
        }
        __builtin_amdgcn_s_setprio(0);
    }

    // epilogue: wave-private repack through Ps (dead), coalesced 16B stores
    const int row = lane >> 2, seg = (lane & 3) * 16;
    #pragma unroll
    for (int i = 0; i < 2; i++) {
        float linv[4];
        #pragma unroll
        for (int r = 0; r < 4; r++) {
            float l = lpart[i][r];
            l += __shfl_xor(l, 1);
            l += __shfl_xor(l, 2);
            l += __shfl_xor(l, 4);
            l += __shfl_xor(l, 8);
            linv[r] = 1.0f / l;
        }
        u16* myl = &Ps[wave * 2048 + i * 1024];   // 16 rows x 64 cols
        #pragma unroll
        for (int j = 0; j < 4; j++)
            #pragma unroll
            for (int r = 0; r < 4; r++)
                myl[(quad * 4 + r) * 64 + j * 16 + r16] = f2bf(O[i][j][r] * linv[r]);
        const int token = tok0 + wave * 32 + i * 16 + row;
        const size_t oidx = (size_t)token * 768 + h * 64 + seg;
        *(ushort8v*)(out + oidx)     = *(const ushort8v*)&myl[row * 64 + seg];
        *(ushort8v*)(out + oidx + 8) = *(const ushort8v*)&myl[row * 64 + seg + 8];
    }
}

// ---------------------------------------------------------------------------
extern "C" void kernel_launch(void* const* d_in, const int* in_sizes, int n_in,
                              void* d_out, int out_size, void* d_ws, size_t ws_size,
                              hipStream_t stream)
{
    (void)in_sizes; (void)n_in; (void)out_size; (void)ws_size;
    const float* x        = (const float*)d_in[0];
    const float* ln1_g    = (const float*)d_in[1];
    const float* ln1_b    = (const float*)d_in[2];
    const float* qkv_w    = (const float*)d_in[3];
    const float* qkv_b    = (const float*)d_in[4];
    const float* proj_w   = (const float*)d_in[5];
    const float* proj_b   = (const float*)d_in[6];
    const float* c_qkv_w  = (const float*)d_in[7];
    const float* c_qkv_b  = (const float*)d_in[8];
    const float* c_proj_w = (const float*)d_in[9];
    const float* c_proj_b = (const float*)d_in[10];
    const float* cp_fc1_w = (const float*)d_in[11];
    const float* cp_fc1_b = (const float*)d_in[12];
    const float* cp_fc2_w = (const float*)d_in[13];
    const float* cp_fc2_b = (const float*)d_in[14];
    const float* P        = (const float*)d_in[15];
    const float* ln2_g    = (const float*)d_in[16];
    const float* ln2_b    = (const float*)d_in[17];
    const float* fc1_w    = (const float*)d_in[18];
    const float* fc1_b    = (const float*)d_in[19];
    const float* fc2_w    = (const float*)d_in[20];
    const float* fc2_b    = (const float*)d_in[21];

    float* out_x    = (float*)d_out;               // (8,1024,768) fp32
    float* out_dmap = out_x + 6291456;             // (8,1024,64)  fp32

    // ws layout (u16 element units)
    u16* us    = (u16*)d_ws;
    u16* n1n2  = us;                         //  6291456  n1 -> zin -> n2
    u16* bigA  = us + 6291456;               // 25165824  qkv/qkv2 ; h(3072)
    u16* ao    = bigA + 18874368;            //  6291456  attn out (tail)
    u16* y     = us + 31457280;              //  6291456
    float* xs  = (float*)(us + 37748736);    //  6291456 fp32
    u16* dmapb = us + 50331648;              //   524288
    u16* cph   = us + 50855936;              //   524288
    u16* Pn    = us + 51380224;              //    49152
    float* invn = (float*)(us + 51429376);   //  8192 fp32
    u16* ci    = us + 51445760;              //  canonical bf16 weights

    u16* w_qkv   = ci;                  // 1769472
    u16* w_proj  = ci + 1769472;        // 589824
    u16* w_cqkv  = ci + 2359296;        // 1769472
    u16* w_cproj = ci + 4128768;        // 589824
    u16* w_cpf1  = ci + 4718592;        // 4096
    u16* w_cpf2  = ci + 4722688;        // 49152
    u16* w_fc1   = ci + 4771840;        // 2359296
    u16* w_fc2   = ci + 7131136;        // 2359296

    // 0. canonicalize weight matrices fp32 -> bf16 (single fused launch)
    {
        ConvArgs a;
        const float* wsrc[8] = { qkv_w, proj_w, c_qkv_w, c_proj_w,
                                 cp_fc1_w, cp_fc2_w, fc1_w, fc2_w };
        u16* wdst[8] = { w_qkv, w_proj, w_cqkv, w_cproj,
                         w_cpf1, w_cpf2, w_fc1, w_fc2 };
        const int wn[8] = { 1769472, 589824, 1769472, 589824,
                            4096, 49152, 2359296, 2359296 };
        int cum = 0;
        for (int i = 0; i < 8; i++) {
            a.src[i] = wsrc[i]; a.dst[i] = wdst[i]; a.n[i] = wn[i];
            a.nblk[i] = cum;
            cum += (wn[i] / 4 + 255) / 256;
        }
        a.nblk[8] = cum;
        conv_all_k<<<cum, 256, 0, stream>>>(a);
    }

    // 1. normalize P rows
    pn_k<<<64, 256, 0, stream>>>(P, Pn);
    // 2. n1 = LN(x), invn = 1/||n1||
    ln_k<true><<<8192, 256, 0, stream>>>(x, ln1_g, ln1_b, n1n2, invn);
    // 3. qkv = n1 @ qkv_w^T + qkv_b   (256^2 4-phase kernel)
    gemm256<F_BIAS | F_OUTB>
        <<<dim3(9, 32), 512, 0, stream>>>(n1n2, w_qkv, qkv_b, bigA,
                                          8192, 2304, 768);
    // 4. attention 1
    attn_mfma<<<dim3(8, 96), 256, 0, stream>>>(bigA, ao);
    // 5. y = ao @ proj_w^T + proj_b
    gemm_mfma<F_BIAS | F_OUTB>
        <<<dim3(6, 64), 256, 0, stream>>>(ao, w_proj, proj_b, nullptr, nullptr,
                                          y, nullptr, 8192, 768, 768);
    // 6. dmap = (n1 @ Pn^T) * invn  -> dmapb bf16 + out_dmap fp32
    gemm_k<64, 64, F_ROWSCALE | F_OUTB | F_OUTF>
        <<<dim3(1, 128), 256, 0, stream>>>(n1n2, Pn, nullptr, invn, nullptr,
                                           nullptr, dmapb, out_dmap, 8192, 64, 768);
    // 7. cph = gelu(dmap @ cp_fc1_w^T + b)
    gemm_k<64, 64, F_BIAS | F_GELU | F_OUTB>
        <<<dim3(1, 128), 256, 0, stream>>>(dmapb, w_cpf1, cp_fc1_b, nullptr,
                                           nullptr, nullptr, cph, nullptr, 8192, 64, 64);
    // 8. zin = cph @ cp_fc2_w^T + b   (zin aliases n1n2)
    gemm_mfma<F_BIAS | F_OUTB>
        <<<dim3(6, 64), 256, 0, stream>>>(cph, w_cpf2, cp_fc2_b, nullptr, nullptr,
                                          n1n2, nullptr, 8192, 768, 64);
    // 9. qkv2 = zin @ c_qkv_w^T + b   (256^2 4-phase kernel)
    gemm256<F_BIAS | F_OUTB>
        <<<dim3(9, 32), 512, 0, stream>>>(n1n2, w_cqkv, c_qkv_b, bigA,
                                          8192, 2304, 768);
    // 10. attention 2
    attn_mfma<<<dim3(8, 96), 256, 0, stream>>>(bigA, ao);
    // 11. xs = ao2 @ c_proj_w^T + b + y + x   (y bf16, x fp32) -> fp32
    gemm_mfma<F_BIAS | F_RES1 | F_RESF | F_OUTF>
        <<<dim3(6, 64), 256, 0, stream>>>(ao, w_cproj, c_proj_b, y, x,
                                          nullptr, xs, 8192, 768, 768);
    // 12. n2 = LN(xs)
    ln_k<false><<<8192, 256, 0, stream>>>(xs, ln2_g, ln2_b, n1n2, nullptr);
    // 13. h = gelu(n2 @ fc1_w^T + b)   (256^2 4-phase kernel)
    gemm256<F_BIAS | F_GELU | F_OUTB>
        <<<dim3(12, 32), 512, 0, stream>>>(n1n2, w_fc1, fc1_b, bigA,
                                           8192, 3072, 768);
    // 14. out = h @ fc2_w^T + b + xs  -> fp32 d_out
    gemm_mfma<F_BIAS | F_RESF | F_OUTF>
        <<<dim3(6, 64), 256, 0, stream>>>(bigA, w_fc2, fc2_b, nullptr, xs,
                                          nullptr, out_x, 8192, 768, 3072);
}

// Round 8
// 547.671 us; speedup vs baseline: 1.0741x; 1.0588x over previous
//
#include <hip/hip_runtime.h>

// ---------------------------------------------------------------------------
// Transformer block w/ SimilarityMaps branch. fp32 inputs/outputs; weights
// canonicalized to bf16; GEMMs + attention on MFMA (16x16x32 bf16).
// B=8 N=1024 C=768 H=12 hd=64 K_PARTS=64 HID=3072. Tokens M = 8192.
// Round 16: REVERT steps 3/9/13 to the 128^2 gemm_mfma (R5 state, 545 us).
//   Both 256^2 variants (R6 coarse, R7 4-phase) measured slower than the
//   simple kernel (75-80 vs 68 us on fc1) -- abandoned. New: steps 6+7
//   (dmap -> gelu cp_fc1) fused into one kernel (row-local chain; each
//   dim3(1,128) block holds its full 64x64 dmap tile), removing a launch
//   and the dmapb round-trip. Numerics preserved via bf16 round-trip in LDS.
// ---------------------------------------------------------------------------

typedef unsigned short u16;
typedef unsigned int   u32;
typedef __attribute__((ext_vector_type(8))) short short8;       // bf16 x8 frag
typedef __attribute__((ext_vector_type(8))) unsigned short ushort8v;
typedef __attribute__((ext_vector_type(4))) float f32x4;        // MFMA accum

#define F_GELU     1
#define F_ROWSCALE 2
#define F_RES1     4    // bf16 residual (res1)
#define F_RESF     8    // fp32 residual (resf)
#define F_OUTB     16   // write bf16 to out
#define F_OUTF     32   // write fp32 to outf
#define F_BIAS     64   // fp32 bias

__device__ __forceinline__ float bf2f(u32 b) { return __uint_as_float(b << 16); }
__device__ __forceinline__ u16 f2bf(float f) {
    u32 u = __float_as_uint(f);
    u32 r = u + 0x7fffu + ((u >> 16) & 1u);   // RNE
    return (u16)(r >> 16);
}
__device__ __forceinline__ u16 f2bf_fast(float f) {
    return (u16)((__float_as_uint(f) + 0x8000u) >> 16);
}
__device__ __forceinline__ float gelu_exact(float v) {
    return 0.5f * v * (1.0f + erff(v * 0.70710678118654752440f));
}
// tanh-form GELU (max abs dev from exact ~3e-3; cheap: 1 transcendental)
__device__ __forceinline__ float gelu_fast(float x) {
    float u = 0.79788456080286535588f * (x + 0.044715f * x * x * x);
    float e = __builtin_amdgcn_exp2f(u * 2.88539008177792681472f);  // exp(2u)
    float t = 1.0f - 2.0f / (e + 1.0f);
    return 0.5f * x * (1.0f + t);
}

// async global->LDS, 16 B per lane; lds base must be wave-uniform
__device__ __forceinline__ void gload16(const u16* g, u16* l) {
    __builtin_amdgcn_global_load_lds(
        (const __attribute__((address_space(1))) u32*)g,
        (__attribute__((address_space(3))) u32*)l, 16, 0, 0);
}

// ---------------- fp32 -> bf16 weight canonicalization (all 8, fused) ------
struct ConvArgs {
    const float* src[8];
    u16*         dst[8];
    int          nblk[9];   // cumulative block offsets
    int          n[8];
};

__global__ __launch_bounds__(256)
void conv_all_k(ConvArgs a)
{
    const int b = blockIdx.x;
    int i = 0;
    #pragma unroll
    for (int j = 0; j < 7; j++) if (b >= a.nblk[j + 1]) i = j + 1;
    const int base = (b - a.nblk[i]) * 1024 + threadIdx.x * 4;
    if (base >= a.n[i]) return;
    float4 v = *(const float4*)(a.src[i] + base);
    ushort4 o;
    o.x = f2bf(v.x); o.y = f2bf(v.y); o.z = f2bf(v.z); o.w = f2bf(v.w);
    *(ushort4*)(a.dst[i] + base) = o;
}

__device__ __forceinline__ float block_sum(float v, float* red) {
    #pragma unroll
    for (int off = 32; off > 0; off >>= 1) v += __shfl_down(v, off);
    __syncthreads();
    if ((threadIdx.x & 63) == 0) red[threadIdx.x >> 6] = v;
    __syncthreads();
    return red[0] + red[1] + red[2] + red[3];
}

// ---------------- LayerNorm over 768 (fp32 in, bf16 out), opt 1/||y|| ------
template<bool NORM>
__global__ __launch_bounds__(256)
void ln_k(const float* __restrict__ xin, const float* __restrict__ g,
          const float* __restrict__ bta, u16* __restrict__ out,
          float* __restrict__ invnorm)
{
    __shared__ float red[4];
    const int row = blockIdx.x, t = threadIdx.x;
    float v[3];
    #pragma unroll
    for (int i = 0; i < 3; i++)
        v[i] = xin[(size_t)row * 768 + t + i * 256];
    float tot = block_sum(v[0] + v[1] + v[2], red);
    float mu  = tot * (1.0f / 768.0f);
    float d0 = v[0] - mu, d1 = v[1] - mu, d2 = v[2] - mu;
    float tot2 = block_sum(d0 * d0 + d1 * d1 + d2 * d2, red);
    float rstd = rsqrtf(tot2 * (1.0f / 768.0f) + 1e-5f);
    float ss = 0.0f;
    #pragma unroll
    for (int i = 0; i < 3; i++) {
        int c = t + i * 256;
        float yy = (v[i] - mu) * rstd * g[c] + bta[c];
        out[(size_t)row * 768 + c] = f2bf(yy);
        ss += yy * yy;
    }
    if constexpr (NORM) {
        float tot3 = block_sum(ss, red);
        if (t == 0) invnorm[row] = rsqrtf(tot3);
    }
}

// ---------------- P row-normalize: Pn = bf16(P / ||P_row||) ----------------
__global__ __launch_bounds__(256)
void pn_k(const float* __restrict__ P, u16* __restrict__ Pn)
{
    __shared__ float red[4];
    const int row = blockIdx.x, t = threadIdx.x;
    float v[3];
    #pragma unroll
    for (int i = 0; i < 3; i++)
        v[i] = P[(size_t)row * 768 + t + i * 256];
    float tot = block_sum(v[0]*v[0] + v[1]*v[1] + v[2]*v[2], red);
    float inv = rsqrtf(tot);
    #pragma unroll
    for (int i = 0; i < 3; i++)
        Pn[(size_t)row * 768 + t + i * 256] = f2bf(v[i] * inv);
}

// ---------------- MFMA GEMM: C[M,N] = A[M,K] * W[N,K]^T (+epilogue) --------
// 128x128 tile, BK=32; 4 waves, each a 64x64 sub-tile. Triple-buffered LDS,
// 2-deep prefetch, one barrier per K-iter. XCD-chunked block order with
// intra-chunk col-grouping (G=6).
template<int FLAGS>
__global__ __launch_bounds__(256)
void gemm_mfma(const u16* __restrict__ A, const u16* __restrict__ W,
               const float* __restrict__ bias,
               const u16* __restrict__ res1, const float* __restrict__ resf,
               u16* __restrict__ out, float* __restrict__ outf,
               int M, int N, int K)
{
    __shared__ u16 smem[3][8192];        // [buf][ As 4096 | Bs 4096 ] = 48 KB
    const int t = threadIdx.x;
    const int wave = t >> 6, lane = t & 63;
    const int nbx  = gridDim.x;
    const int orig = blockIdx.x + blockIdx.y * nbx;
    const int cpx  = (nbx * gridDim.y) >> 3;   // wgs per XCD chunk
    const int xcd  = orig & 7, loc = orig >> 3;
    const int Rc   = cpx / nbx;                // rows per chunk (8 here)
    const int gsz  = 6 * Rc;                   // wgs per col-group
    const int grp  = loc / gsz;
    const int rem  = loc - grp * gsz;
    const int ccol = grp * 6 + rem % 6;
    const int crow = xcd * Rc + rem / 6;
    const int m0 = crow * 128, n0 = ccol * 128;
    const int Wm = (wave >> 1) * 64, Wn = (wave & 1) * 64;
    const int rr = lane >> 2, cc = (lane & 3) * 8;
    const int quad = lane >> 4, r16 = lane & 15;
    const int NK = K >> 5;

    f32x4 acc[4][4];
    #pragma unroll
    for (int i = 0; i < 4; i++)
        #pragma unroll
        for (int j = 0; j < 4; j++)
            acc[i][j] = (f32x4){0.f, 0.f, 0.f, 0.f};

    // prologue: stage k-tiles 0 and 1 into bufs 0,1 (order matters for vmcnt)
    #pragma unroll
    for (int c = 0; c < 2; c++) {
        const int chunk = wave * 2 + c;
        const int row = chunk * 16 + rr;
        gload16(A + (size_t)(m0 + row) * K + cc, &smem[0][chunk * 512]);
        gload16(W + (size_t)(n0 + row) * K + cc, &smem[0][4096 + chunk * 512]);
    }
    if (NK > 1) {
        #pragma unroll
        for (int c = 0; c < 2; c++) {
            const int chunk = wave * 2 + c;
            const int row = chunk * 16 + rr;
            gload16(A + (size_t)(m0 + row) * K + 32 + cc, &smem[1][chunk * 512]);
            gload16(W + (size_t)(n0 + row) * K + 32 + cc, &smem[1][4096 + chunk * 512]);
        }
    }

    for (int kt = 0; kt < NK; kt++) {
        const int cur = kt % 3;
        if (kt + 1 < NK)
            asm volatile("s_waitcnt vmcnt(4)\n\ts_barrier" ::: "memory");
        else
            asm volatile("s_waitcnt vmcnt(0)\n\ts_barrier" ::: "memory");
        if (kt + 2 < NK) {
            const int k0 = (kt + 2) * 32;
            const int nb = (kt + 2) % 3;
            #pragma unroll
            for (int c = 0; c < 2; c++) {
                const int chunk = wave * 2 + c;
                const int row = chunk * 16 + rr;
                gload16(A + (size_t)(m0 + row) * K + k0 + cc,
                        &smem[nb][chunk * 512]);
                gload16(W + (size_t)(n0 + row) * K + k0 + cc,
                        &smem[nb][4096 + chunk * 512]);
            }
        }
        short8 af[4], bfr[4];
        #pragma unroll
        for (int i = 0; i < 4; i++) {
            af[i]  = *(const short8*)&smem[cur][(Wm + i * 16 + r16) * 32 + quad * 8];
            bfr[i] = *(const short8*)&smem[cur][4096 + (Wn + i * 16 + r16) * 32 + quad * 8];
        }
        #pragma unroll
        for (int i = 0; i < 4; i++)
            #pragma unroll
            for (int j = 0; j < 4; j++)
                acc[i][j] = __builtin_amdgcn_mfma_f32_16x16x32_bf16(
                    af[i], bfr[j], acc[i][j], 0, 0, 0);
    }
    __syncthreads();

    // ---- epilogue: wave-private fp32 repack (no cross-wave sync) ----
    float* myl = (float*)&smem[0][0] + wave * 1088;   // 16 rows x 68 cols fp32
    float bj[4];
    #pragma unroll
    for (int j = 0; j < 4; j++) {
        if constexpr (FLAGS & F_BIAS) bj[j] = bias[n0 + Wn + j * 16 + r16];
        else bj[j] = 0.0f;
    }
    const int row = lane >> 2, seg = (lane & 3) * 16;

    #pragma unroll
    for (int i = 0; i < 4; i++) {
        #pragma unroll
        for (int j = 0; j < 4; j++)
            #pragma unroll
            for (int r = 0; r < 4; r++) {
                float v = acc[i][j][r] + bj[j];
                if constexpr (FLAGS & F_GELU) v = gelu_fast(v);
                myl[(quad * 4 + r) * 68 + j * 16 + r16] = v;
            }
        float v[16];
        #pragma unroll
        for (int k4 = 0; k4 < 4; k4++) {
            float4 f = *(const float4*)&myl[row * 68 + seg + k4 * 4];
            v[k4 * 4 + 0] = f.x; v[k4 * 4 + 1] = f.y;
            v[k4 * 4 + 2] = f.z; v[k4 * 4 + 3] = f.w;
        }
        const int m = m0 + Wm + i * 16 + row;
        const size_t idx = (size_t)m * N + n0 + Wn + seg;
        if constexpr (FLAGS & F_RES1) {
            ushort8v r0 = *(const ushort8v*)(res1 + idx);
            ushort8v r1 = *(const ushort8v*)(res1 + idx + 8);
            #pragma unroll
            for (int k = 0; k < 8; k++) { v[k] += bf2f(r0[k]); v[k + 8] += bf2f(r1[k]); }
        }
        if constexpr (FLAGS & F_RESF) {
            #pragma unroll
            for (int k4 = 0; k4 < 4; k4++) {
                float4 f = *(const float4*)(resf + idx + k4 * 4);
                v[k4 * 4 + 0] += f.x; v[k4 * 4 + 1] += f.y;
                v[k4 * 4 + 2] += f.z; v[k4 * 4 + 3] += f.w;
            }
        }
        if constexpr (FLAGS & F_OUTB) {
            ushort8v o0, o1;
            #pragma unroll
            for (int k = 0; k < 8; k++) { o0[k] = f2bf(v[k]); o1[k] = f2bf(v[k + 8]); }
            *(ushort8v*)(out + idx) = o0;
            *(ushort8v*)(out + idx + 8) = o1;
        }
        if constexpr (FLAGS & F_OUTF) {
            #pragma unroll
            for (int k4 = 0; k4 < 4; k4++) {
                float4 f = {v[k4 * 4 + 0], v[k4 * 4 + 1], v[k4 * 4 + 2], v[k4 * 4 + 3]};
                *(float4*)(outf + idx + k4 * 4) = f;
            }
        }
    }
}

// ---------------- small fp32 GEMM (64x64 tiles) for the K-parts branch -----
template<int BM, int BN, int FLAGS>
__global__ __launch_bounds__(256)
void gemm_k(const u16* __restrict__ A, const u16* __restrict__ W,
            const float* __restrict__ bias, const float* __restrict__ rowscale,
            const u16* __restrict__ res1, const float* __restrict__ resf,
            u16* __restrict__ out, float* __restrict__ outf,
            int M, int N, int K)
{
    constexpr int RM = BM / 16, RN = BN / 16;
    __shared__ float Asm[16][BM + 4];
    __shared__ float Wsm[16][BN + 4];
    const int t  = threadIdx.x;
    const int tx = t & 15, ty = t >> 4;
    const int m0 = blockIdx.y * BM, n0 = blockIdx.x * BN;

    float acc[RM][RN];
    #pragma unroll
    for (int i = 0; i < RM; i++)
        #pragma unroll
        for (int j = 0; j < RN; j++) acc[i][j] = 0.0f;

    for (int k0 = 0; k0 < K; k0 += 16) {
        #pragma unroll
        for (int i = 0; i < BM / 64; i++) {
            int f = t + i * 256, r = f >> 2, c4 = (f & 3) << 2;
            uint2 u = *(const uint2*)(A + (size_t)(m0 + r) * K + k0 + c4);
            Asm[c4 + 0][r] = bf2f(u.x & 0xffffu);
            Asm[c4 + 1][r] = bf2f(u.x >> 16);
            Asm[c4 + 2][r] = bf2f(u.y & 0xffffu);
            Asm[c4 + 3][r] = bf2f(u.y >> 16);
        }
        #pragma unroll
        for (int i = 0; i < BN / 64; i++) {
            int f = t + i * 256, r = f >> 2, c4 = (f & 3) << 2;
            uint2 u = *(const uint2*)(W + (size_t)(n0 + r) * K + k0 + c4);
            Wsm[c4 + 0][r] = bf2f(u.x & 0xffffu);
            Wsm[c4 + 1][r] = bf2f(u.x >> 16);
            Wsm[c4 + 2][r] = bf2f(u.y & 0xffffu);
            Wsm[c4 + 3][r] = bf2f(u.y >> 16);
        }
        __syncthreads();
        #pragma unroll
        for (int k = 0; k < 16; k++) {
            float a[RM], w[RN];
            #pragma unroll
            for (int ii = 0; ii < RM; ii += 4) {
                float4 v = *(const float4*)&Asm[k][ty * RM + ii];
                a[ii] = v.x; a[ii + 1] = v.y; a[ii + 2] = v.z; a[ii + 3] = v.w;
            }
            #pragma unroll
            for (int jj = 0; jj < RN; jj += 4) {
                float4 v = *(const float4*)&Wsm[k][tx * RN + jj];
                w[jj] = v.x; w[jj + 1] = v.y; w[jj + 2] = v.z; w[jj + 3] = v.w;
            }
            #pragma unroll
            for (int i = 0; i < RM; i++)
                #pragma unroll
                for (int j = 0; j < RN; j++)
                    acc[i][j] = fmaf(a[i], w[j], acc[i][j]);
        }
        __syncthreads();
    }

    #pragma unroll
    for (int i = 0; i < RM; i++) {
        const int m = m0 + ty * RM + i;
        float rs = 1.0f;
        if constexpr (FLAGS & F_ROWSCALE) rs = rowscale[m];
        #pragma unroll
        for (int jj = 0; jj < RN; jj += 4) {
            const int n = n0 + tx * RN + jj;
            const size_t idx = (size_t)m * N + n;
            float b4[4] = {0.f, 0.f, 0.f, 0.f};
            if constexpr (FLAGS & F_BIAS) {
                float4 bvv = *(const float4*)(bias + n);
                b4[0] = bvv.x; b4[1] = bvv.y; b4[2] = bvv.z; b4[3] = bvv.w;
            }
            float e[4];
            #pragma unroll
            for (int j = 0; j < 4; j++) {
                float v = acc[i][jj + j];
                if constexpr (FLAGS & F_BIAS) v += b4[j];
                if constexpr (FLAGS & F_GELU) v = gelu_exact(v);
                if constexpr (FLAGS & F_ROWSCALE) v *= rs;
                e[j] = v;
            }
            if constexpr (FLAGS & F_OUTB) {
                ushort4 o4;
                o4.x = f2bf(e[0]); o4.y = f2bf(e[1]);
                o4.z = f2bf(e[2]); o4.w = f2bf(e[3]);
                *(ushort4*)(out + idx) = o4;
            }
            if constexpr (FLAGS & F_OUTF) {
                float4 o4 = {e[0], e[1], e[2], e[3]};
                *(float4*)(outf + idx) = o4;
            }
        }
    }
}

// ---------------- fused: dmap = (n1 @ Pn^T)*invn ; cph = gelu(dmap@W1^T+b) --
// One 64-row block owns the full 64x64 dmap tile (N=64), so the row-local
// cp_fc1 GEMM (K=64) runs in-block. Writes out_dmap fp32 + cph bf16.
// Numerics identical to the former two-kernel path: dmap is round-tripped
// through bf16 (Dsm) before the fc1 GEMM, exactly like the dmapb buffer was.
__global__ __launch_bounds__(256)
void dmap_fused_k(const u16* __restrict__ A, const u16* __restrict__ Pn,
                  const float* __restrict__ invn,
                  const u16* __restrict__ w1, const float* __restrict__ b1,
                  float* __restrict__ dmap_f, u16* __restrict__ cph)
{
    __shared__ float Asm[16][68];
    __shared__ float Wsm[16][68];
    __shared__ u16 Dsm[64][66];   // bf16 dmap tile (round-trip)
    __shared__ u16 W1s[64][66];   // cp_fc1 weights
    const int t  = threadIdx.x;
    const int tx = t & 15, ty = t >> 4;
    const int m0 = blockIdx.x * 64;

    // stage W1 (64x64 bf16) once; padded stride 66 (2-way max on reads)
    {
        const int r = t >> 2, c = (t & 3) * 16;
        #pragma unroll
        for (int k = 0; k < 16; k++)
            W1s[r][c + k] = w1[r * 64 + c + k];
    }

    float acc[4][4];
    #pragma unroll
    for (int i = 0; i < 4; i++)
        #pragma unroll
        for (int j = 0; j < 4; j++) acc[i][j] = 0.0f;

    for (int k0 = 0; k0 < 768; k0 += 16) {
        {
            int r = t >> 2, c4 = (t & 3) << 2;
            uint2 u = *(const uint2*)(A + (size_t)(m0 + r) * 768 + k0 + c4);
            Asm[c4 + 0][r] = bf2f(u.x & 0xffffu);
            Asm[c4 + 1][r] = bf2f(u.x >> 16);
            Asm[c4 + 2][r] = bf2f(u.y & 0xffffu);
            Asm[c4 + 3][r] = bf2f(u.y >> 16);
        }
        {
            int r = t >> 2, c4 = (t & 3) << 2;
            uint2 u = *(const uint2*)(Pn + (size_t)r * 768 + k0 + c4);
            Wsm[c4 + 0][r] = bf2f(u.x & 0xffffu);
            Wsm[c4 + 1][r] = bf2f(u.x >> 16);
            Wsm[c4 + 2][r] = bf2f(u.y & 0xffffu);
            Wsm[c4 + 3][r] = bf2f(u.y >> 16);
        }
        __syncthreads();
        #pragma unroll
        for (int k = 0; k < 16; k++) {
            float a[4], w[4];
            float4 va = *(const float4*)&Asm[k][ty * 4];
            a[0] = va.x; a[1] = va.y; a[2] = va.z; a[3] = va.w;
            float4 vw = *(const float4*)&Wsm[k][tx * 4];
            w[0] = vw.x; w[1] = vw.y; w[2] = vw.z; w[3] = vw.w;
            #pragma unroll
            for (int i = 0; i < 4; i++)
                #pragma unroll
                for (int j = 0; j < 4; j++)
                    acc[i][j] = fmaf(a[i], w[j], acc[i][j]);
        }
        __syncthreads();
    }

    // epilogue A: rowscale, write fp32 dmap out, stash bf16 into Dsm
    #pragma unroll
    for (int i = 0; i < 4; i++) {
        const int m = m0 + ty * 4 + i;
        const float rs = invn[m];
        float4 o4;
        float e0 = acc[i][0] * rs, e1 = acc[i][1] * rs;
        float e2 = acc[i][2] * rs, e3 = acc[i][3] * rs;
        o4.x = e0; o4.y = e1; o4.z = e2; o4.w = e3;
        *(float4*)(dmap_f + (size_t)m * 64 + tx * 4) = o4;
        const int rl = ty * 4 + i;
        Dsm[rl][tx * 4 + 0] = f2bf(e0);
        Dsm[rl][tx * 4 + 1] = f2bf(e1);
        Dsm[rl][tx * 4 + 2] = f2bf(e2);
        Dsm[rl][tx * 4 + 3] = f2bf(e3);
    }
    __syncthreads();

    // phase 2: cph = gelu_exact(D @ W1^T + b1), K=64
    float acc2[4][4];
    #pragma unroll
    for (int i = 0; i < 4; i++)
        #pragma unroll
        for (int j = 0; j < 4; j++) acc2[i][j] = 0.0f;
    for (int k4 = 0; k4 < 16; k4++) {
        float d[4][4], w[4][4];
        #pragma unroll
        for (int i = 0; i < 4; i++) {
            u32 u0 = *(const u32*)&Dsm[ty * 4 + i][k4 * 4];
            u32 u1 = *(const u32*)&Dsm[ty * 4 + i][k4 * 4 + 2];
            d[i][0] = bf2f(u0 & 0xffffu); d[i][1] = bf2f(u0 >> 16);
            d[i][2] = bf2f(u1 & 0xffffu); d[i][3] = bf2f(u1 >> 16);
        }
        #pragma unroll
        for (int j = 0; j < 4; j++) {
            u32 u0 = *(const u32*)&W1s[tx * 4 + j][k4 * 4];
            u32 u1 = *(const u32*)&W1s[tx * 4 + j][k4 * 4 + 2];
            w[j][0] = bf2f(u0 & 0xffffu); w[j][1] = bf2f(u0 >> 16);
            w[j][2] = bf2f(u1 & 0xffffu); w[j][3] = bf2f(u1 >> 16);
        }
        #pragma unroll
        for (int i = 0; i < 4; i++)
            #pragma unroll
            for (int j = 0; j < 4; j++)
                #pragma unroll
                for (int kk = 0; kk < 4; kk++)
                    acc2[i][j] = fmaf(d[i][kk], w[j][kk], acc2[i][j]);
    }
    {
        float4 bv = *(const float4*)(b1 + tx * 4);
        float b4[4] = {bv.x, bv.y, bv.z, bv.w};
        #pragma unroll
        for (int i = 0; i < 4; i++) {
            const int m = m0 + ty * 4 + i;
            ushort4 o4;
            o4.x = f2bf(gelu_exact(acc2[i][0] + b4[0]));
            o4.y = f2bf(gelu_exact(acc2[i][1] + b4[1]));
            o4.z = f2bf(gelu_exact(acc2[i][2] + b4[2]));
            o4.w = f2bf(gelu_exact(acc2[i][3] + b4[3]));
            *(ushort4*)(cph + (size_t)m * 64 + tx * 4) = o4;
        }
    }
}

// ---------------- MFMA flash attention (bf16, max-free online softmax) ----
// Staging for tile kt+1 (K-DMA + V reg loads) is issued between softmax and
// PV of tile kt, so HBM/L2 latency hides under PV + the next barrier.
__global__ __launch_bounds__(256)
void attn_mfma(const u16* __restrict__ qkv, u16* __restrict__ out)
{
    const int orig = blockIdx.x + blockIdx.y * 8;
    const int wg   = (orig & 7) * 96 + (orig >> 3);
    const int qt = wg & 7;                // 0..7  (128-row q tiles)
    const int bh = wg >> 3;               // 0..95
    const int b = bh / 12, h = bh % 12;
    __shared__ u16 Qs[2 * 128 * 32];      // 16 KB
    __shared__ u16 Ks[2 * 64 * 32];       //  8 KB
    __shared__ u16 Vt[2 * 64 * 32];       //  8 KB  (transposed: rows = d)
    __shared__ u16 Ps[2 * 128 * 32];      // 16 KB; epilogue: 4 waves x 2 x 16x64
    const int t = threadIdx.x;
    const int wave = t >> 6, lane = t & 63;
    const int quad = lane >> 4, r16 = lane & 15;
    const size_t RS = 2304;
    const int tok0 = b * 1024 + qt * 128;
    const u16* qbase = qkv + (size_t)tok0 * RS + h * 64;
    const float SC = 0.125f * 1.44269504088896340736f;   // scale * log2(e)

    #pragma unroll
    for (int c = 0; c < 4; c++) {
        int idx = wave * 4 + c;
        int kc = idx >> 3, rg = idx & 7;
        int row = rg * 16 + (lane >> 2);
        gload16(qbase + (size_t)row * RS + kc * 32 + (lane & 3) * 8,
                &Qs[kc * 4096 + rg * 512]);
    }

    f32x4 O[2][4];
    float lpart[2][4];
    #pragma unroll
    for (int i = 0; i < 2; i++)
        #pragma unroll
        for (int j = 0; j < 4; j++) {
            O[i][j] = (f32x4){0.f, 0.f, 0.f, 0.f};
            lpart[i][j & 3] = 0.0f;
        }

    // staging helpers
    const int kp = t & 63, dg = t >> 6;
    const int vb = (kp >> 5) * 2048 + (kp & 31);
    uint2 vr[4];

    // prologue: stage kt=0 (K-DMA into Ks, V into regs)
    {
        const u16* kbase = qkv + (size_t)(b * 1024) * RS + 768 + h * 64;
        #pragma unroll
        for (int c = 0; c < 2; c++) {
            int idx = wave * 2 + c;
            int kc = idx >> 2, rg = idx & 3;
            int row = rg * 16 + (lane >> 2);
            gload16(kbase + (size_t)row * RS + kc * 32 + (lane & 3) * 8,
                    &Ks[kc * 2048 + rg * 512]);
        }
        const u16* vbase = qkv + (size_t)(b * 1024) * RS + 1536 + h * 64;
        #pragma unroll
        for (int it = 0; it < 4; it++) {
            int d0 = dg * 16 + it * 4;
            vr[it] = *(const uint2*)(vbase + (size_t)kp * RS + d0);
        }
    }

    for (int kt = 0; kt < 16; kt++) {
        // (a) drains K-DMA + V loads (+ Q on first iter); gates Vt/Ps reuse
        __syncthreads();
        // write V regs -> Vt (transposed)
        #pragma unroll
        for (int it = 0; it < 4; it++) {
            int d0 = dg * 16 + it * 4;
            uint2 u = vr[it];
            Vt[vb + (d0 + 0) * 32] = (u16)(u.x & 0xffffu);
            Vt[vb + (d0 + 1) * 32] = (u16)(u.x >> 16);
            Vt[vb + (d0 + 2) * 32] = (u16)(u.y & 0xffffu);
            Vt[vb + (d0 + 3) * 32] = (u16)(u.y >> 16);
        }

        f32x4 S[2][4];
        #pragma unroll
        for (int i = 0; i < 2; i++)
            #pragma unroll
            for (int j = 0; j < 4; j++)
                S[i][j] = (f32x4){0.f, 0.f, 0.f, 0.f};
        __builtin_amdgcn_s_setprio(1);
        #pragma unroll
        for (int kc = 0; kc < 2; kc++) {
            short8 aq[2], bk[4];
            #pragma unroll
            for (int i = 0; i < 2; i++)
                aq[i] = *(const short8*)&Qs[kc * 4096 + (wave * 32 + i * 16 + r16) * 32 + quad * 8];
            #pragma unroll
            for (int j = 0; j < 4; j++)
                bk[j] = *(const short8*)&Ks[kc * 2048 + (j * 16 + r16) * 32 + quad * 8];
            #pragma unroll
            for (int i = 0; i < 2; i++)
                #pragma unroll
                for (int j = 0; j < 4; j++)
                    S[i][j] = __builtin_amdgcn_mfma_f32_16x16x32_bf16(
                        aq[i], bk[j], S[i][j], 0, 0, 0);
        }
        __builtin_amdgcn_s_setprio(0);

        #pragma unroll
        for (int i = 0; i < 2; i++) {
            #pragma unroll
            for (int j = 0; j < 4; j++) {
                const int col = j * 16 + r16;
                const int pb = (col >> 5) * 4096 + (col & 31);
                #pragma unroll
                for (int r = 0; r < 4; r++) {
                    float p = __builtin_amdgcn_exp2f(S[i][j][r] * SC);
                    lpart[i][r] += p;
                    const int row = wave * 32 + i * 16 + quad * 4 + r;
                    Ps[pb + row * 32] = f2bf_fast(p);
                }
            }
        }

        // (b) all waves past QK^T (Ks dead) and Ps fully written
        __syncthreads();

        if (kt < 15) {
            const u16* kbase = qkv + (size_t)(b * 1024 + (kt + 1) * 64) * RS + 768 + h * 64;
            #pragma unroll
            for (int c = 0; c < 2; c++) {
                int idx = wave * 2 + c;
                int kc = idx >> 2, rg = idx & 3;
                int row = rg * 16 + (lane >> 2);
                gload16(kbase + (size_t)row * RS + kc * 32 + (lane & 3) * 8,
                        &Ks[kc * 2048 + rg * 512]);
            }
            const u16* vbase = qkv + (size_t)(b * 1024 + (kt + 1) * 64) * RS + 1536 + h * 64;
            #pragma unroll
            for (int it = 0; it < 4; it++) {
                int d0 = dg * 16 + it * 4;
                vr[it] = *(const uint2*)(vbase + (size_t)kp * RS + d0);
            }
        }

        __builtin_amdgcn_s_setprio(1);
        #pragma unroll
        for (int kc = 0; kc < 2; kc++) {
            short8 ap[2], bv[4];
            #pragma unroll
            for (int i = 0; i < 2; i++)
                ap[i] = *(const short8*)&Ps[kc * 4096 + (wave * 32 + i * 16 + r16) * 32 + quad * 8];
            #pragma unroll
            for (int j = 0; j < 4; j++)
                bv[j] = *(const short8*)&Vt[kc * 2048 + (j * 16 + r16) * 32 + quad * 8];
            #pragma unroll
            for (int i = 0; i < 2; i++)
                #pragma unroll
                for (int j = 0; j < 4; j++)
                    O[i][j] = __builtin_amdgcn_mfma_f32_16x16x32_bf16(
                        ap[i], bv[j], O[i][j], 0, 0, 0);
        }
        __builtin_amdgcn_s_setprio(0);
    }

    // epilogue: wave-private repack through Ps (dead), coalesced 16B stores
    const int row = lane >> 2, seg = (lane & 3) * 16;
    #pragma unroll
    for (int i = 0; i < 2; i++) {
        float linv[4];
        #pragma unroll
        for (int r = 0; r < 4; r++) {
            float l = lpart[i][r];
            l += __shfl_xor(l, 1);
            l += __shfl_xor(l, 2);
            l += __shfl_xor(l, 4);
            l += __shfl_xor(l, 8);
            linv[r] = 1.0f / l;
        }
        u16* myl = &Ps[wave * 2048 + i * 1024];   // 16 rows x 64 cols
        #pragma unroll
        for (int j = 0; j < 4; j++)
            #pragma unroll
            for (int r = 0; r < 4; r++)
                myl[(quad * 4 + r) * 64 + j * 16 + r16] = f2bf(O[i][j][r] * linv[r]);
        const int token = tok0 + wave * 32 + i * 16 + row;
        const size_t oidx = (size_t)token * 768 + h * 64 + seg;
        *(ushort8v*)(out + oidx)     = *(const ushort8v*)&myl[row * 64 + seg];
        *(ushort8v*)(out + oidx + 8) = *(const ushort8v*)&myl[row * 64 + seg + 8];
    }
}

// ---------------------------------------------------------------------------
extern "C" void kernel_launch(void* const* d_in, const int* in_sizes, int n_in,
                              void* d_out, int out_size, void* d_ws, size_t ws_size,
                              hipStream_t stream)
{
    (void)in_sizes; (void)n_in; (void)out_size; (void)ws_size;
    const float* x        = (const float*)d_in[0];
    const float* ln1_g    = (const float*)d_in[1];
    const float* ln1_b    = (const float*)d_in[2];
    const float* qkv_w    = (const float*)d_in[3];
    const float* qkv_b    = (const float*)d_in[4];
    const float* proj_w   = (const float*)d_in[5];
    const float* proj_b   = (const float*)d_in[6];
    const float* c_qkv_w  = (const float*)d_in[7];
    const float* c_qkv_b  = (const float*)d_in[8];
    const float* c_proj_w = (const float*)d_in[9];
    const float* c_proj_b = (const float*)d_in[10];
    const float* cp_fc1_w = (const float*)d_in[11];
    const float* cp_fc1_b = (const float*)d_in[12];
    const float* cp_fc2_w = (const float*)d_in[13];
    const float* cp_fc2_b = (const float*)d_in[14];
    const float* P        = (const float*)d_in[15];
    const float* ln2_g    = (const float*)d_in[16];
    const float* ln2_b    = (const float*)d_in[17];
    const float* fc1_w    = (const float*)d_in[18];
    const float* fc1_b    = (const float*)d_in[19];
    const float* fc2_w    = (const float*)d_in[20];
    const float* fc2_b    = (const float*)d_in[21];

    float* out_x    = (float*)d_out;               // (8,1024,768) fp32
    float* out_dmap = out_x + 6291456;             // (8,1024,64)  fp32

    // ws layout (u16 element units)
    u16* us    = (u16*)d_ws;
    u16* n1n2  = us;                         //  6291456  n1 -> zin -> n2
    u16* bigA  = us + 6291456;               // 25165824  qkv/qkv2 ; h(3072)
    u16* ao    = bigA + 18874368;            //  6291456  attn out (tail)
    u16* y     = us + 31457280;              //  6291456
    float* xs  = (float*)(us + 37748736);    //  6291456 fp32
    u16* dmapb = us + 50331648;              //   524288 (unused after fusion)
    u16* cph   = us + 50855936;              //   524288
    u16* Pn    = us + 51380224;              //    49152
    float* invn = (float*)(us + 51429376);   //  8192 fp32
    u16* ci    = us + 51445760;              //  canonical bf16 weights
    (void)dmapb;

    u16* w_qkv   = ci;                  // 1769472
    u16* w_proj  = ci + 1769472;        // 589824
    u16* w_cqkv  = ci + 2359296;        // 1769472
    u16* w_cproj = ci + 4128768;        // 589824
    u16* w_cpf1  = ci + 4718592;        // 4096
    u16* w_cpf2  = ci + 4722688;        // 49152
    u16* w_fc1   = ci + 4771840;        // 2359296
    u16* w_fc2   = ci + 7131136;        // 2359296

    // 0. canonicalize weight matrices fp32 -> bf16 (single fused launch)
    {
        ConvArgs a;
        const float* wsrc[8] = { qkv_w, proj_w, c_qkv_w, c_proj_w,
                                 cp_fc1_w, cp_fc2_w, fc1_w, fc2_w };
        u16* wdst[8] = { w_qkv, w_proj, w_cqkv, w_cproj,
                         w_cpf1, w_cpf2, w_fc1, w_fc2 };
        const int wn[8] = { 1769472, 589824, 1769472, 589824,
                            4096, 49152, 2359296, 2359296 };
        int cum = 0;
        for (int i = 0; i < 8; i++) {
            a.src[i] = wsrc[i]; a.dst[i] = wdst[i]; a.n[i] = wn[i];
            a.nblk[i] = cum;
            cum += (wn[i] / 4 + 255) / 256;
        }
        a.nblk[8] = cum;
        conv_all_k<<<cum, 256, 0, stream>>>(a);
    }

    // 1. normalize P rows
    pn_k<<<64, 256, 0, stream>>>(P, Pn);
    // 2. n1 = LN(x), invn = 1/||n1||
    ln_k<true><<<8192, 256, 0, stream>>>(x, ln1_g, ln1_b, n1n2, invn);
    // 3. qkv = n1 @ qkv_w^T + qkv_b
    gemm_mfma<F_BIAS | F_OUTB>
        <<<dim3(18, 64), 256, 0, stream>>>(n1n2, w_qkv, qkv_b, nullptr, nullptr,
                                           bigA, nullptr, 8192, 2304, 768);
    // 4. attention 1
    attn_mfma<<<dim3(8, 96), 256, 0, stream>>>(bigA, ao);
    // 5. y = ao @ proj_w^T + proj_b
    gemm_mfma<F_BIAS | F_OUTB>
        <<<dim3(6, 64), 256, 0, stream>>>(ao, w_proj, proj_b, nullptr, nullptr,
                                          y, nullptr, 8192, 768, 768);
    // 6+7. dmap (fp32 out) + cph = gelu(dmap @ cp_fc1^T + b), fused
    dmap_fused_k<<<128, 256, 0, stream>>>(n1n2, Pn, invn, w_cpf1, cp_fc1_b,
                                          out_dmap, cph);
    // 8. zin = cph @ cp_fc2_w^T + b   (zin aliases n1n2)
    gemm_mfma<F_BIAS | F_OUTB>
        <<<dim3(6, 64), 256, 0, stream>>>(cph, w_cpf2, cp_fc2_b, nullptr, nullptr,
                                          n1n2, nullptr, 8192, 768, 64);
    // 9. qkv2 = zin @ c_qkv_w^T + b
    gemm_mfma<F_BIAS | F_OUTB>
        <<<dim3(18, 64), 256, 0, stream>>>(n1n2, w_cqkv, c_qkv_b, nullptr, nullptr,
                                           bigA, nullptr, 8192, 2304, 768);
    // 10. attention 2
    attn_mfma<<<dim3(8, 96), 256, 0, stream>>>(bigA, ao);
    // 11. xs = ao2 @ c_proj_w^T + b + y + x   (y bf16, x fp32) -> fp32
    gemm_mfma<F_BIAS | F_RES1 | F_RESF | F_OUTF>
        <<<dim3(6, 64), 256, 0, stream>>>(ao, w_cproj, c_proj_b, y, x,
                                          nullptr, xs, 8192, 768, 768);
    // 12. n2 = LN(xs)
    ln_k<false><<<8192, 256, 0, stream>>>(xs, ln2_g, ln2_b, n1n2, nullptr);
    // 13. h = gelu(n2 @ fc1_w^T + b)
    gemm_mfma<F_BIAS | F_GELU | F_OUTB>
        <<<dim3(24, 64), 256, 0, stream>>>(n1n2, w_fc1, fc1_b, nullptr, nullptr,
                                           bigA, nullptr, 8192, 3072, 768);
    // 14. out = h @ fc2_w^T + b + xs  -> fp32 d_out
    gemm_mfma<F_BIAS | F_RESF | F_OUTF>
        <<<dim3(6, 64), 256, 0, stream>>>(bigA, w_fc2, fc2_b, nullptr, xs,
                                          nullptr, out_x, 8192, 768, 3072);
}

// Round 9
// 535.022 us; speedup vs baseline: 1.0995x; 1.0236x over previous
//
#include <hip/hip_runtime.h>

// ---------------------------------------------------------------------------
// Transformer block w/ SimilarityMaps branch. fp32 inputs/outputs; weights
// canonicalized to bf16; GEMMs + attention on MFMA (16x16x32 bf16).
// B=8 N=1024 C=768 H=12 hd=64 K_PARTS=64 HID=3072. Tokens M = 8192.
// Round 17: scheduling-only round (GEMM inner structure frozen at the
//   proven 128^2 kernel). (a) prep_k fuses conv+pn+ln1 into one launch;
//   (b) dmap_fused moved before qkv (deps allow it); (c) gemm_pair_k runs
//   proj (K=768) and zin (K=64) co-resident in one 768-block launch --
//   each alone is 384 blocks = 1.5 blocks/CU (half machine idle).
//   14 -> 11 dispatches.
// ---------------------------------------------------------------------------

typedef unsigned short u16;
typedef unsigned int   u32;
typedef __attribute__((ext_vector_type(8))) short short8;       // bf16 x8 frag
typedef __attribute__((ext_vector_type(8))) unsigned short ushort8v;
typedef __attribute__((ext_vector_type(4))) float f32x4;        // MFMA accum

#define F_GELU     1
#define F_RES1     4    // bf16 residual (res1)
#define F_RESF     8    // fp32 residual (resf)
#define F_OUTB     16   // write bf16 to out
#define F_OUTF     32   // write fp32 to outf
#define F_BIAS     64   // fp32 bias

__device__ __forceinline__ float bf2f(u32 b) { return __uint_as_float(b << 16); }
__device__ __forceinline__ u16 f2bf(float f) {
    u32 u = __float_as_uint(f);
    u32 r = u + 0x7fffu + ((u >> 16) & 1u);   // RNE
    return (u16)(r >> 16);
}
__device__ __forceinline__ u16 f2bf_fast(float f) {
    return (u16)((__float_as_uint(f) + 0x8000u) >> 16);
}
__device__ __forceinline__ float gelu_exact(float v) {
    return 0.5f * v * (1.0f + erff(v * 0.70710678118654752440f));
}
// tanh-form GELU (max abs dev from exact ~3e-3; cheap: 1 transcendental)
__device__ __forceinline__ float gelu_fast(float x) {
    float u = 0.79788456080286535588f * (x + 0.044715f * x * x * x);
    float e = __builtin_amdgcn_exp2f(u * 2.88539008177792681472f);  // exp(2u)
    float t = 1.0f - 2.0f / (e + 1.0f);
    return 0.5f * x * (1.0f + t);
}

// async global->LDS, 16 B per lane; lds base must be wave-uniform
__device__ __forceinline__ void gload16(const u16* g, u16* l) {
    __builtin_amdgcn_global_load_lds(
        (const __attribute__((address_space(1))) u32*)g,
        (__attribute__((address_space(3))) u32*)l, 16, 0, 0);
}

// ---------------- prologue bodies (conv / pn / ln) -------------------------
struct ConvArgs {
    const float* src[8];
    u16*         dst[8];
    int          nblk[9];   // cumulative block offsets
    int          n[8];
};

__device__ __forceinline__ void conv_body(const ConvArgs& a, int b)
{
    int i = 0;
    #pragma unroll
    for (int j = 0; j < 7; j++) if (b >= a.nblk[j + 1]) i = j + 1;
    const int base = (b - a.nblk[i]) * 1024 + threadIdx.x * 4;
    if (base >= a.n[i]) return;
    float4 v = *(const float4*)(a.src[i] + base);
    ushort4 o;
    o.x = f2bf(v.x); o.y = f2bf(v.y); o.z = f2bf(v.z); o.w = f2bf(v.w);
    *(ushort4*)(a.dst[i] + base) = o;
}

__device__ __forceinline__ float block_sum(float v, float* red) {
    #pragma unroll
    for (int off = 32; off > 0; off >>= 1) v += __shfl_down(v, off);
    __syncthreads();
    if ((threadIdx.x & 63) == 0) red[threadIdx.x >> 6] = v;
    __syncthreads();
    return red[0] + red[1] + red[2] + red[3];
}

__device__ __forceinline__ void pn_body(const float* __restrict__ P,
                                        u16* __restrict__ Pn, int row, float* red)
{
    const int t = threadIdx.x;
    float v[3];
    #pragma unroll
    for (int i = 0; i < 3; i++)
        v[i] = P[(size_t)row * 768 + t + i * 256];
    float tot = block_sum(v[0]*v[0] + v[1]*v[1] + v[2]*v[2], red);
    float inv = rsqrtf(tot);
    #pragma unroll
    for (int i = 0; i < 3; i++)
        Pn[(size_t)row * 768 + t + i * 256] = f2bf(v[i] * inv);
}

template<bool NORM>
__device__ __forceinline__ void ln_body(const float* __restrict__ xin,
                                        const float* __restrict__ g,
                                        const float* __restrict__ bta,
                                        u16* __restrict__ out,
                                        float* __restrict__ invnorm,
                                        int row, float* red)
{
    const int t = threadIdx.x;
    float v[3];
    #pragma unroll
    for (int i = 0; i < 3; i++)
        v[i] = xin[(size_t)row * 768 + t + i * 256];
    float tot = block_sum(v[0] + v[1] + v[2], red);
    float mu  = tot * (1.0f / 768.0f);
    float d0 = v[0] - mu, d1 = v[1] - mu, d2 = v[2] - mu;
    float tot2 = block_sum(d0 * d0 + d1 * d1 + d2 * d2, red);
    float rstd = rsqrtf(tot2 * (1.0f / 768.0f) + 1e-5f);
    float ss = 0.0f;
    #pragma unroll
    for (int i = 0; i < 3; i++) {
        int c = t + i * 256;
        float yy = (v[i] - mu) * rstd * g[c] + bta[c];
        out[(size_t)row * 768 + c] = f2bf(yy);
        ss += yy * yy;
    }
    if constexpr (NORM) {
        float tot3 = block_sum(ss, red);
        if (t == 0) invnorm[row] = rsqrtf(tot3);
    }
}

// fused prologue: conv (weights) + pn (P rows) + ln1 (x) in one launch
struct PrepArgs {
    ConvArgs conv;
    const float* P;   u16* Pn;
    const float* x;   const float* g; const float* bta;
    u16* n1;          float* invn;
    int conv_blocks;
};

__global__ __launch_bounds__(256)
void prep_k(PrepArgs pa)
{
    __shared__ float red[4];
    const int b = blockIdx.x;
    if (b < pa.conv_blocks) {
        conv_body(pa.conv, b);
    } else if (b < pa.conv_blocks + 64) {
        pn_body(pa.P, pa.Pn, b - pa.conv_blocks, red);
    } else {
        ln_body<true>(pa.x, pa.g, pa.bta, pa.n1, pa.invn,
                      b - pa.conv_blocks - 64, red);
    }
}

// standalone LN (step 12)
template<bool NORM>
__global__ __launch_bounds__(256)
void ln_k(const float* __restrict__ xin, const float* __restrict__ g,
          const float* __restrict__ bta, u16* __restrict__ out,
          float* __restrict__ invnorm)
{
    __shared__ float red[4];
    ln_body<NORM>(xin, g, bta, out, invnorm, blockIdx.x, red);
}

// ---------------- MFMA GEMM body: C[M,N] = A[M,K] * W[N,K]^T ---------------
// 128x128 tile, BK=32; 4 waves, each a 64x64 sub-tile. Triple-buffered LDS,
// 2-deep prefetch, one barrier per K-iter. XCD-chunked block order with
// intra-chunk col-grouping (G=6). smem_ = 3*8192 u16 (48 KB).
template<int FLAGS>
__device__ __forceinline__
void gemm_body(int orig, int nbx, int nby,
               const u16* __restrict__ A, const u16* __restrict__ W,
               const float* __restrict__ bias,
               const u16* __restrict__ res1, const float* __restrict__ resf,
               u16* __restrict__ out, float* __restrict__ outf,
               int M, int N, int K, u16* smem_)
{
    const int t = threadIdx.x;
    const int wave = t >> 6, lane = t & 63;
    const int cpx  = (nbx * nby) >> 3;         // wgs per XCD chunk
    const int xcd  = orig & 7, loc = orig >> 3;
    const int Rc   = cpx / nbx;                // rows per chunk
    const int gsz  = 6 * Rc;                   // wgs per col-group
    const int grp  = loc / gsz;
    const int rem  = loc - grp * gsz;
    const int ccol = grp * 6 + rem % 6;
    const int crow = xcd * Rc + rem / 6;
    const int m0 = crow * 128, n0 = ccol * 128;
    const int Wm = (wave >> 1) * 64, Wn = (wave & 1) * 64;
    const int rr = lane >> 2, cc = (lane & 3) * 8;
    const int quad = lane >> 4, r16 = lane & 15;
    const int NK = K >> 5;

    f32x4 acc[4][4];
    #pragma unroll
    for (int i = 0; i < 4; i++)
        #pragma unroll
        for (int j = 0; j < 4; j++)
            acc[i][j] = (f32x4){0.f, 0.f, 0.f, 0.f};

    // prologue: stage k-tiles 0 and 1 into bufs 0,1 (order matters for vmcnt)
    #pragma unroll
    for (int c = 0; c < 2; c++) {
        const int chunk = wave * 2 + c;
        const int row = chunk * 16 + rr;
        gload16(A + (size_t)(m0 + row) * K + cc, smem_ + chunk * 512);
        gload16(W + (size_t)(n0 + row) * K + cc, smem_ + 4096 + chunk * 512);
    }
    if (NK > 1) {
        #pragma unroll
        for (int c = 0; c < 2; c++) {
            const int chunk = wave * 2 + c;
            const int row = chunk * 16 + rr;
            gload16(A + (size_t)(m0 + row) * K + 32 + cc, smem_ + 8192 + chunk * 512);
            gload16(W + (size_t)(n0 + row) * K + 32 + cc, smem_ + 12288 + chunk * 512);
        }
    }

    for (int kt = 0; kt < NK; kt++) {
        const int cur = kt % 3;
        if (kt + 1 < NK)
            asm volatile("s_waitcnt vmcnt(4)\n\ts_barrier" ::: "memory");
        else
            asm volatile("s_waitcnt vmcnt(0)\n\ts_barrier" ::: "memory");
        if (kt + 2 < NK) {
            const int k0 = (kt + 2) * 32;
            const int nb = (kt + 2) % 3;
            #pragma unroll
            for (int c = 0; c < 2; c++) {
                const int chunk = wave * 2 + c;
                const int row = chunk * 16 + rr;
                gload16(A + (size_t)(m0 + row) * K + k0 + cc,
                        smem_ + nb * 8192 + chunk * 512);
                gload16(W + (size_t)(n0 + row) * K + k0 + cc,
                        smem_ + nb * 8192 + 4096 + chunk * 512);
            }
        }
        short8 af[4], bfr[4];
        #pragma unroll
        for (int i = 0; i < 4; i++) {
            af[i]  = *(const short8*)&smem_[cur * 8192 + (Wm + i * 16 + r16) * 32 + quad * 8];
            bfr[i] = *(const short8*)&smem_[cur * 8192 + 4096 + (Wn + i * 16 + r16) * 32 + quad * 8];
        }
        #pragma unroll
        for (int i = 0; i < 4; i++)
            #pragma unroll
            for (int j = 0; j < 4; j++)
                acc[i][j] = __builtin_amdgcn_mfma_f32_16x16x32_bf16(
                    af[i], bfr[j], acc[i][j], 0, 0, 0);
    }
    __syncthreads();

    // ---- epilogue: wave-private fp32 repack (no cross-wave sync) ----
    float* myl = (float*)smem_ + wave * 1088;   // 16 rows x 68 cols fp32
    float bj[4];
    #pragma unroll
    for (int j = 0; j < 4; j++) {
        if constexpr (FLAGS & F_BIAS) bj[j] = bias[n0 + Wn + j * 16 + r16];
        else bj[j] = 0.0f;
    }
    const int row = lane >> 2, seg = (lane & 3) * 16;

    #pragma unroll
    for (int i = 0; i < 4; i++) {
        #pragma unroll
        for (int j = 0; j < 4; j++)
            #pragma unroll
            for (int r = 0; r < 4; r++) {
                float v = acc[i][j][r] + bj[j];
                if constexpr (FLAGS & F_GELU) v = gelu_fast(v);
                myl[(quad * 4 + r) * 68 + j * 16 + r16] = v;
            }
        float v[16];
        #pragma unroll
        for (int k4 = 0; k4 < 4; k4++) {
            float4 f = *(const float4*)&myl[row * 68 + seg + k4 * 4];
            v[k4 * 4 + 0] = f.x; v[k4 * 4 + 1] = f.y;
            v[k4 * 4 + 2] = f.z; v[k4 * 4 + 3] = f.w;
        }
        const int m = m0 + Wm + i * 16 + row;
        const size_t idx = (size_t)m * N + n0 + Wn + seg;
        if constexpr (FLAGS & F_RES1) {
            ushort8v r0 = *(const ushort8v*)(res1 + idx);
            ushort8v r1 = *(const ushort8v*)(res1 + idx + 8);
            #pragma unroll
            for (int k = 0; k < 8; k++) { v[k] += bf2f(r0[k]); v[k + 8] += bf2f(r1[k]); }
        }
        if constexpr (FLAGS & F_RESF) {
            #pragma unroll
            for (int k4 = 0; k4 < 4; k4++) {
                float4 f = *(const float4*)(resf + idx + k4 * 4);
                v[k4 * 4 + 0] += f.x; v[k4 * 4 + 1] += f.y;
                v[k4 * 4 + 2] += f.z; v[k4 * 4 + 3] += f.w;
            }
        }
        if constexpr (FLAGS & F_OUTB) {
            ushort8v o0, o1;
            #pragma unroll
            for (int k = 0; k < 8; k++) { o0[k] = f2bf(v[k]); o1[k] = f2bf(v[k + 8]); }
            *(ushort8v*)(out + idx) = o0;
            *(ushort8v*)(out + idx + 8) = o1;
        }
        if constexpr (FLAGS & F_OUTF) {
            #pragma unroll
            for (int k4 = 0; k4 < 4; k4++) {
                float4 f = {v[k4 * 4 + 0], v[k4 * 4 + 1], v[k4 * 4 + 2], v[k4 * 4 + 3]};
                *(float4*)(outf + idx + k4 * 4) = f;
            }
        }
    }
}

template<int FLAGS>
__global__ __launch_bounds__(256)
void gemm_mfma(const u16* __restrict__ A, const u16* __restrict__ W,
               const float* __restrict__ bias,
               const u16* __restrict__ res1, const float* __restrict__ resf,
               u16* __restrict__ out, float* __restrict__ outf,
               int M, int N, int K)
{
    __shared__ u16 smem[3][8192];
    gemm_body<FLAGS>(blockIdx.x + blockIdx.y * gridDim.x, gridDim.x, gridDim.y,
                     A, W, bias, res1, resf, out, outf, M, N, K, &smem[0][0]);
}

// proj (K=768) and zin (K=64) co-resident: blocks [0,384) proj, [384,768) zin.
// Both are F_BIAS|F_OUTB 8192x768 GEMMs on a virtual (6,64) grid.
__global__ __launch_bounds__(256)
void gemm_pair_k(const u16* __restrict__ A0, const u16* __restrict__ W0,
                 const float* __restrict__ b0, u16* __restrict__ o0, int K0,
                 const u16* __restrict__ A1, const u16* __restrict__ W1,
                 const float* __restrict__ b1, u16* __restrict__ o1, int K1)
{
    __shared__ u16 smem[3][8192];
    if (blockIdx.x < 384)
        gemm_body<F_BIAS | F_OUTB>(blockIdx.x, 6, 64, A0, W0, b0,
                                   nullptr, nullptr, o0, nullptr,
                                   8192, 768, K0, &smem[0][0]);
    else
        gemm_body<F_BIAS | F_OUTB>(blockIdx.x - 384, 6, 64, A1, W1, b1,
                                   nullptr, nullptr, o1, nullptr,
                                   8192, 768, K1, &smem[0][0]);
}

// ---------------- fused: dmap = (n1 @ Pn^T)*invn ; cph = gelu(dmap@W1^T+b) --
__global__ __launch_bounds__(256)
void dmap_fused_k(const u16* __restrict__ A, const u16* __restrict__ Pn,
                  const float* __restrict__ invn,
                  const u16* __restrict__ w1, const float* __restrict__ b1,
                  float* __restrict__ dmap_f, u16* __restrict__ cph)
{
    __shared__ float Asm[16][68];
    __shared__ float Wsm[16][68];
    __shared__ u16 Dsm[64][66];   // bf16 dmap tile (round-trip)
    __shared__ u16 W1s[64][66];   // cp_fc1 weights
    const int t  = threadIdx.x;
    const int tx = t & 15, ty = t >> 4;
    const int m0 = blockIdx.x * 64;

    {
        const int r = t >> 2, c = (t & 3) * 16;
        #pragma unroll
        for (int k = 0; k < 16; k++)
            W1s[r][c + k] = w1[r * 64 + c + k];
    }

    float acc[4][4];
    #pragma unroll
    for (int i = 0; i < 4; i++)
        #pragma unroll
        for (int j = 0; j < 4; j++) acc[i][j] = 0.0f;

    for (int k0 = 0; k0 < 768; k0 += 16) {
        {
            int r = t >> 2, c4 = (t & 3) << 2;
            uint2 u = *(const uint2*)(A + (size_t)(m0 + r) * 768 + k0 + c4);
            Asm[c4 + 0][r] = bf2f(u.x & 0xffffu);
            Asm[c4 + 1][r] = bf2f(u.x >> 16);
            Asm[c4 + 2][r] = bf2f(u.y & 0xffffu);
            Asm[c4 + 3][r] = bf2f(u.y >> 16);
        }
        {
            int r = t >> 2, c4 = (t & 3) << 2;
            uint2 u = *(const uint2*)(Pn + (size_t)r * 768 + k0 + c4);
            Wsm[c4 + 0][r] = bf2f(u.x & 0xffffu);
            Wsm[c4 + 1][r] = bf2f(u.x >> 16);
            Wsm[c4 + 2][r] = bf2f(u.y & 0xffffu);
            Wsm[c4 + 3][r] = bf2f(u.y >> 16);
        }
        __syncthreads();
        #pragma unroll
        for (int k = 0; k < 16; k++) {
            float a[4], w[4];
            float4 va = *(const float4*)&Asm[k][ty * 4];
            a[0] = va.x; a[1] = va.y; a[2] = va.z; a[3] = va.w;
            float4 vw = *(const float4*)&Wsm[k][tx * 4];
            w[0] = vw.x; w[1] = vw.y; w[2] = vw.z; w[3] = vw.w;
            #pragma unroll
            for (int i = 0; i < 4; i++)
                #pragma unroll
                for (int j = 0; j < 4; j++)
                    acc[i][j] = fmaf(a[i], w[j], acc[i][j]);
        }
        __syncthreads();
    }

    #pragma unroll
    for (int i = 0; i < 4; i++) {
        const int m = m0 + ty * 4 + i;
        const float rs = invn[m];
        float4 o4;
        float e0 = acc[i][0] * rs, e1 = acc[i][1] * rs;
        float e2 = acc[i][2] * rs, e3 = acc[i][3] * rs;
        o4.x = e0; o4.y = e1; o4.z = e2; o4.w = e3;
        *(float4*)(dmap_f + (size_t)m * 64 + tx * 4) = o4;
        const int rl = ty * 4 + i;
        Dsm[rl][tx * 4 + 0] = f2bf(e0);
        Dsm[rl][tx * 4 + 1] = f2bf(e1);
        Dsm[rl][tx * 4 + 2] = f2bf(e2);
        Dsm[rl][tx * 4 + 3] = f2bf(e3);
    }
    __syncthreads();

    float acc2[4][4];
    #pragma unroll
    for (int i = 0; i < 4; i++)
        #pragma unroll
        for (int j = 0; j < 4; j++) acc2[i][j] = 0.0f;
    for (int k4 = 0; k4 < 16; k4++) {
        float d[4][4], w[4][4];
        #pragma unroll
        for (int i = 0; i < 4; i++) {
            u32 u0 = *(const u32*)&Dsm[ty * 4 + i][k4 * 4];
            u32 u1 = *(const u32*)&Dsm[ty * 4 + i][k4 * 4 + 2];
            d[i][0] = bf2f(u0 & 0xffffu); d[i][1] = bf2f(u0 >> 16);
            d[i][2] = bf2f(u1 & 0xffffu); d[i][3] = bf2f(u1 >> 16);
        }
        #pragma unroll
        for (int j = 0; j < 4; j++) {
            u32 u0 = *(const u32*)&W1s[tx * 4 + j][k4 * 4];
            u32 u1 = *(const u32*)&W1s[tx * 4 + j][k4 * 4 + 2];
            w[j][0] = bf2f(u0 & 0xffffu); w[j][1] = bf2f(u0 >> 16);
            w[j][2] = bf2f(u1 & 0xffffu); w[j][3] = bf2f(u1 >> 16);
        }
        #pragma unroll
        for (int i = 0; i < 4; i++)
            #pragma unroll
            for (int j = 0; j < 4; j++)
                #pragma unroll
                for (int kk = 0; kk < 4; kk++)
                    acc2[i][j] = fmaf(d[i][kk], w[j][kk], acc2[i][j]);
    }
    {
        float4 bv = *(const float4*)(b1 + tx * 4);
        float b4[4] = {bv.x, bv.y, bv.z, bv.w};
        #pragma unroll
        for (int i = 0; i < 4; i++) {
            const int m = m0 + ty * 4 + i;
            ushort4 o4;
            o4.x = f2bf(gelu_exact(acc2[i][0] + b4[0]));
            o4.y = f2bf(gelu_exact(acc2[i][1] + b4[1]));
            o4.z = f2bf(gelu_exact(acc2[i][2] + b4[2]));
            o4.w = f2bf(gelu_exact(acc2[i][3] + b4[3]));
            *(ushort4*)(cph + (size_t)m * 64 + tx * 4) = o4;
        }
    }
}

// ---------------- MFMA flash attention (bf16, max-free online softmax) ----
__global__ __launch_bounds__(256)
void attn_mfma(const u16* __restrict__ qkv, u16* __restrict__ out)
{
    const int orig = blockIdx.x + blockIdx.y * 8;
    const int wg   = (orig & 7) * 96 + (orig >> 3);
    const int qt = wg & 7;                // 0..7  (128-row q tiles)
    const int bh = wg >> 3;               // 0..95
    const int b = bh / 12, h = bh % 12;
    __shared__ u16 Qs[2 * 128 * 32];      // 16 KB
    __shared__ u16 Ks[2 * 64 * 32];       //  8 KB
    __shared__ u16 Vt[2 * 64 * 32];       //  8 KB  (transposed: rows = d)
    __shared__ u16 Ps[2 * 128 * 32];      // 16 KB; epilogue: 4 waves x 2 x 16x64
    const int t = threadIdx.x;
    const int wave = t >> 6, lane = t & 63;
    const int quad = lane >> 4, r16 = lane & 15;
    const size_t RS = 2304;
    const int tok0 = b * 1024 + qt * 128;
    const u16* qbase = qkv + (size_t)tok0 * RS + h * 64;
    const float SC = 0.125f * 1.44269504088896340736f;   // scale * log2(e)

    #pragma unroll
    for (int c = 0; c < 4; c++) {
        int idx = wave * 4 + c;
        int kc = idx >> 3, rg = idx & 7;
        int row = rg * 16 + (lane >> 2);
        gload16(qbase + (size_t)row * RS + kc * 32 + (lane & 3) * 8,
                &Qs[kc * 4096 + rg * 512]);
    }

    f32x4 O[2][4];
    float lpart[2][4];
    #pragma unroll
    for (int i = 0; i < 2; i++)
        #pragma unroll
        for (int j = 0; j < 4; j++) {
            O[i][j] = (f32x4){0.f, 0.f, 0.f, 0.f};
            lpart[i][j & 3] = 0.0f;
        }

    // staging helpers
    const int kp = t & 63, dg = t >> 6;
    const int vb = (kp >> 5) * 2048 + (kp & 31);
    uint2 vr[4];

    // prologue: stage kt=0 (K-DMA into Ks, V into regs)
    {
        const u16* kbase = qkv + (size_t)(b * 1024) * RS + 768 + h * 64;
        #pragma unroll
        for (int c = 0; c < 2; c++) {
            int idx = wave * 2 + c;
            int kc = idx >> 2, rg = idx & 3;
            int row = rg * 16 + (lane >> 2);
            gload16(kbase + (size_t)row * RS + kc * 32 + (lane & 3) * 8,
                    &Ks[kc * 2048 + rg * 512]);
        }
        const u16* vbase = qkv + (size_t)(b * 1024) * RS + 1536 + h * 64;
        #pragma unroll
        for (int it = 0; it < 4; it++) {
            int d0 = dg * 16 + it * 4;
            vr[it] = *(const uint2*)(vbase + (size_t)kp * RS + d0);
        }
    }

    for (int kt = 0; kt < 16; kt++) {
        __syncthreads();
        #pragma unroll
        for (int it = 0; it < 4; it++) {
            int d0 = dg * 16 + it * 4;
            uint2 u = vr[it];
            Vt[vb + (d0 + 0) * 32] = (u16)(u.x & 0xffffu);
            Vt[vb + (d0 + 1) * 32] = (u16)(u.x >> 16);
            Vt[vb + (d0 + 2) * 32] = (u16)(u.y & 0xffffu);
            Vt[vb + (d0 + 3) * 32] = (u16)(u.y >> 16);
        }

        f32x4 S[2][4];
        #pragma unroll
        for (int i = 0; i < 2; i++)
            #pragma unroll
            for (int j = 0; j < 4; j++)
                S[i][j] = (f32x4){0.f, 0.f, 0.f, 0.f};
        __builtin_amdgcn_s_setprio(1);
        #pragma unroll
        for (int kc = 0; kc < 2; kc++) {
            short8 aq[2], bk[4];
            #pragma unroll
            for (int i = 0; i < 2; i++)
                aq[i] = *(const short8*)&Qs[kc * 4096 + (wave * 32 + i * 16 + r16) * 32 + quad * 8];
            #pragma unroll
            for (int j = 0; j < 4; j++)
                bk[j] = *(const short8*)&Ks[kc * 2048 + (j * 16 + r16) * 32 + quad * 8];
            #pragma unroll
            for (int i = 0; i < 2; i++)
                #pragma unroll
                for (int j = 0; j < 4; j++)
                    S[i][j] = __builtin_amdgcn_mfma_f32_16x16x32_bf16(
                        aq[i], bk[j], S[i][j], 0, 0, 0);
        }
        __builtin_amdgcn_s_setprio(0);

        #pragma unroll
        for (int i = 0; i < 2; i++) {
            #pragma unroll
            for (int j = 0; j < 4; j++) {
                const int col = j * 16 + r16;
                const int pb = (col >> 5) * 4096 + (col & 31);
                #pragma unroll
                for (int r = 0; r < 4; r++) {
                    float p = __builtin_amdgcn_exp2f(S[i][j][r] * SC);
                    lpart[i][r] += p;
                    const int row = wave * 32 + i * 16 + quad * 4 + r;
                    Ps[pb + row * 32] = f2bf_fast(p);
                }
            }
        }

        __syncthreads();

        if (kt < 15) {
            const u16* kbase = qkv + (size_t)(b * 1024 + (kt + 1) * 64) * RS + 768 + h * 64;
            #pragma unroll
            for (int c = 0; c < 2; c++) {
                int idx = wave * 2 + c;
                int kc = idx >> 2, rg = idx & 3;
                int row = rg * 16 + (lane >> 2);
                gload16(kbase + (size_t)row * RS + kc * 32 + (lane & 3) * 8,
                        &Ks[kc * 2048 + rg * 512]);
            }
            const u16* vbase = qkv + (size_t)(b * 1024 + (kt + 1) * 64) * RS + 1536 + h * 64;
            #pragma unroll
            for (int it = 0; it < 4; it++) {
                int d0 = dg * 16 + it * 4;
                vr[it] = *(const uint2*)(vbase + (size_t)kp * RS + d0);
            }
        }

        __builtin_amdgcn_s_setprio(1);
        #pragma unroll
        for (int kc = 0; kc < 2; kc++) {
            short8 ap[2], bv[4];
            #pragma unroll
            for (int i = 0; i < 2; i++)
                ap[i] = *(const short8*)&Ps[kc * 4096 + (wave * 32 + i * 16 + r16) * 32 + quad * 8];
            #pragma unroll
            for (int j = 0; j < 4; j++)
                bv[j] = *(const short8*)&Vt[kc * 2048 + (j * 16 + r16) * 32 + quad * 8];
            #pragma unroll
            for (int i = 0; i < 2; i++)
                #pragma unroll
                for (int j = 0; j < 4; j++)
                    O[i][j] = __builtin_amdgcn_mfma_f32_16x16x32_bf16(
                        ap[i], bv[j], O[i][j], 0, 0, 0);
        }
        __builtin_amdgcn_s_setprio(0);
    }

    // epilogue: wave-private repack through Ps (dead), coalesced 16B stores
    const int row = lane >> 2, seg = (lane & 3) * 16;
    #pragma unroll
    for (int i = 0; i < 2; i++) {
        float linv[4];
        #pragma unroll
        for (int r = 0; r < 4; r++) {
            float l = lpart[i][r];
            l += __shfl_xor(l, 1);
            l += __shfl_xor(l, 2);
            l += __shfl_xor(l, 4);
            l += __shfl_xor(l, 8);
            linv[r] = 1.0f / l;
        }
        u16* myl = &Ps[wave * 2048 + i * 1024];   // 16 rows x 64 cols
        #pragma unroll
        for (int j = 0; j < 4; j++)
            #pragma unroll
            for (int r = 0; r < 4; r++)
                myl[(quad * 4 + r) * 64 + j * 16 + r16] = f2bf(O[i][j][r] * linv[r]);
        const int token = tok0 + wave * 32 + i * 16 + row;
        const size_t oidx = (size_t)token * 768 + h * 64 + seg;
        *(ushort8v*)(out + oidx)     = *(const ushort8v*)&myl[row * 64 + seg];
        *(ushort8v*)(out + oidx + 8) = *(const ushort8v*)&myl[row * 64 + seg + 8];
    }
}

// ---------------------------------------------------------------------------
extern "C" void kernel_launch(void* const* d_in, const int* in_sizes, int n_in,
                              void* d_out, int out_size, void* d_ws, size_t ws_size,
                              hipStream_t stream)
{
    (void)in_sizes; (void)n_in; (void)out_size; (void)ws_size;
    const float* x        = (const float*)d_in[0];
    const float* ln1_g    = (const float*)d_in[1];
    const float* ln1_b    = (const float*)d_in[2];
    const float* qkv_w    = (const float*)d_in[3];
    const float* qkv_b    = (const float*)d_in[4];
    const float* proj_w   = (const float*)d_in[5];
    const float* proj_b   = (const float*)d_in[6];
    const float* c_qkv_w  = (const float*)d_in[7];
    const float* c_qkv_b  = (const float*)d_in[8];
    const float* c_proj_w = (const float*)d_in[9];
    const float* c_proj_b = (const float*)d_in[10];
    const float* cp_fc1_w = (const float*)d_in[11];
    const float* cp_fc1_b = (const float*)d_in[12];
    const float* cp_fc2_w = (const float*)d_in[13];
    const float* cp_fc2_b = (const float*)d_in[14];
    const float* P        = (const float*)d_in[15];
    const float* ln2_g    = (const float*)d_in[16];
    const float* ln2_b    = (const float*)d_in[17];
    const float* fc1_w    = (const float*)d_in[18];
    const float* fc1_b    = (const float*)d_in[19];
    const float* fc2_w    = (const float*)d_in[20];
    const float* fc2_b    = (const float*)d_in[21];

    float* out_x    = (float*)d_out;               // (8,1024,768) fp32
    float* out_dmap = out_x + 6291456;             // (8,1024,64)  fp32

    // ws layout (u16 element units)
    u16* us    = (u16*)d_ws;
    u16* n1n2  = us;                         //  6291456  n1 -> zin -> n2
    u16* bigA  = us + 6291456;               // 25165824  qkv/qkv2 ; h(3072)
    u16* ao    = bigA + 18874368;            //  6291456  attn out (tail)
    u16* y     = us + 31457280;              //  6291456
    float* xs  = (float*)(us + 37748736);    //  6291456 fp32
    u16* cph   = us + 50855936;              //   524288
    u16* Pn    = us + 51380224;              //    49152
    float* invn = (float*)(us + 51429376);   //  8192 fp32
    u16* ci    = us + 51445760;              //  canonical bf16 weights

    u16* w_qkv   = ci;                  // 1769472
    u16* w_proj  = ci + 1769472;        // 589824
    u16* w_cqkv  = ci + 2359296;        // 1769472
    u16* w_cproj = ci + 4128768;        // 589824
    u16* w_cpf1  = ci + 4718592;        // 4096
    u16* w_cpf2  = ci + 4722688;        // 49152
    u16* w_fc1   = ci + 4771840;        // 2359296
    u16* w_fc2   = ci + 7131136;        // 2359296

    // 0-2. fused prologue: weight conv + P-normalize + LN1
    {
        PrepArgs pa;
        const float* wsrc[8] = { qkv_w, proj_w, c_qkv_w, c_proj_w,
                                 cp_fc1_w, cp_fc2_w, fc1_w, fc2_w };
        u16* wdst[8] = { w_qkv, w_proj, w_cqkv, w_cproj,
                         w_cpf1, w_cpf2, w_fc1, w_fc2 };
        const int wn[8] = { 1769472, 589824, 1769472, 589824,
                            4096, 49152, 2359296, 2359296 };
        int cum = 0;
        for (int i = 0; i < 8; i++) {
            pa.conv.src[i] = wsrc[i]; pa.conv.dst[i] = wdst[i];
            pa.conv.n[i] = wn[i];
            pa.conv.nblk[i] = cum;
            cum += (wn[i] / 4 + 255) / 256;
        }
        pa.conv.nblk[8] = cum;
        pa.conv_blocks = cum;
        pa.P = P; pa.Pn = Pn;
        pa.x = x; pa.g = ln1_g; pa.bta = ln1_b;
        pa.n1 = n1n2; pa.invn = invn;
        prep_k<<<cum + 64 + 8192, 256, 0, stream>>>(pa);
    }

    // dmap branch head (needs only prep outputs): dmap fp32 + cph
    dmap_fused_k<<<128, 256, 0, stream>>>(n1n2, Pn, invn, w_cpf1, cp_fc1_b,
                                          out_dmap, cph);
    // 3. qkv = n1 @ qkv_w^T + qkv_b
    gemm_mfma<F_BIAS | F_OUTB>
        <<<dim3(18, 64), 256, 0, stream>>>(n1n2, w_qkv, qkv_b, nullptr, nullptr,
                                           bigA, nullptr, 8192, 2304, 768);
    // 4. attention 1
    attn_mfma<<<dim3(8, 96), 256, 0, stream>>>(bigA, ao);
    // 5+8. co-resident: y = ao @ proj_w^T + b  ||  zin = cph @ cp_fc2_w^T + b
    //      (zin overwrites n1n2; its readers qkv/dmap completed above)
    gemm_pair_k<<<768, 256, 0, stream>>>(ao, w_proj, proj_b, y, 768,
                                         cph, w_cpf2, cp_fc2_b, n1n2, 64);
    // 9. qkv2 = zin @ c_qkv_w^T + b
    gemm_mfma<F_BIAS | F_OUTB>
        <<<dim3(18, 64), 256, 0, stream>>>(n1n2, w_cqkv, c_qkv_b, nullptr, nullptr,
                                           bigA, nullptr, 8192, 2304, 768);
    // 10. attention 2
    attn_mfma<<<dim3(8, 96), 256, 0, stream>>>(bigA, ao);
    // 11. xs = ao2 @ c_proj_w^T + b + y + x   (y bf16, x fp32) -> fp32
    gemm_mfma<F_BIAS | F_RES1 | F_RESF | F_OUTF>
        <<<dim3(6, 64), 256, 0, stream>>>(ao, w_cproj, c_proj_b, y, x,
                                          nullptr, xs, 8192, 768, 768);
    // 12. n2 = LN(xs)
    ln_k<false><<<8192, 256, 0, stream>>>(xs, ln2_g, ln2_b, n1n2, nullptr);
    // 13. h = gelu(n2 @ fc1_w^T + b)
    gemm_mfma<F_BIAS | F_GELU | F_OUTB>
        <<<dim3(24, 64), 256, 0, stream>>>(n1n2, w_fc1, fc1_b, nullptr, nullptr,
                                           bigA, nullptr, 8192, 3072, 768);
    // 14. out = h @ fc2_w^T + b + xs  -> fp32 d_out
    gemm_mfma<F_BIAS | F_RESF | F_OUTF>
        <<<dim3(6, 64), 256, 0, stream>>>(bigA, w_fc2, fc2_b, nullptr, xs,
                                          nullptr, out_x, 8192, 768, 3072);
}

// Round 10
// 508.344 us; speedup vs baseline: 1.1572x; 1.0525x over previous
//
#include <hip/hip_runtime.h>

// ---------------------------------------------------------------------------
// Transformer block w/ SimilarityMaps branch. fp32 inputs/outputs; weights
// canonicalized to bf16; GEMMs + attention on MFMA (16x16x32 bf16).
// B=8 N=1024 C=768 H=12 hd=64 K_PARTS=64 HID=3072. Tokens M = 8192.
// Round 18: merge dmap_fused into the qkv launch (qkv_dmap_k, 1280 blocks;
//   dmap blocks first so they run from t=0 inside qkv's shadow). Both only
//   read prep outputs and write disjoint buffers -- pure ILP between
//   dispatches, same trick as R17's proj||zin pair. 10 -> 9 dispatches.
//   GEMM inner structure frozen (128^2, 3-buf, 2-deep, 1-barrier).
// ---------------------------------------------------------------------------

typedef unsigned short u16;
typedef unsigned int   u32;
typedef __attribute__((ext_vector_type(8))) short short8;       // bf16 x8 frag
typedef __attribute__((ext_vector_type(8))) unsigned short ushort8v;
typedef __attribute__((ext_vector_type(4))) float f32x4;        // MFMA accum

#define F_GELU     1
#define F_RES1     4    // bf16 residual (res1)
#define F_RESF     8    // fp32 residual (resf)
#define F_OUTB     16   // write bf16 to out
#define F_OUTF     32   // write fp32 to outf
#define F_BIAS     64   // fp32 bias

__device__ __forceinline__ float bf2f(u32 b) { return __uint_as_float(b << 16); }
__device__ __forceinline__ u16 f2bf(float f) {
    u32 u = __float_as_uint(f);
    u32 r = u + 0x7fffu + ((u >> 16) & 1u);   // RNE
    return (u16)(r >> 16);
}
__device__ __forceinline__ u16 f2bf_fast(float f) {
    return (u16)((__float_as_uint(f) + 0x8000u) >> 16);
}
__device__ __forceinline__ float gelu_exact(float v) {
    return 0.5f * v * (1.0f + erff(v * 0.70710678118654752440f));
}
// tanh-form GELU (max abs dev from exact ~3e-3; cheap: 1 transcendental)
__device__ __forceinline__ float gelu_fast(float x) {
    float u = 0.79788456080286535588f * (x + 0.044715f * x * x * x);
    float e = __builtin_amdgcn_exp2f(u * 2.88539008177792681472f);  // exp(2u)
    float t = 1.0f - 2.0f / (e + 1.0f);
    return 0.5f * x * (1.0f + t);
}

// async global->LDS, 16 B per lane; lds base must be wave-uniform
__device__ __forceinline__ void gload16(const u16* g, u16* l) {
    __builtin_amdgcn_global_load_lds(
        (const __attribute__((address_space(1))) u32*)g,
        (__attribute__((address_space(3))) u32*)l, 16, 0, 0);
}

// ---------------- prologue bodies (conv / pn / ln) -------------------------
struct ConvArgs {
    const float* src[8];
    u16*         dst[8];
    int          nblk[9];   // cumulative block offsets
    int          n[8];
};

__device__ __forceinline__ void conv_body(const ConvArgs& a, int b)
{
    int i = 0;
    #pragma unroll
    for (int j = 0; j < 7; j++) if (b >= a.nblk[j + 1]) i = j + 1;
    const int base = (b - a.nblk[i]) * 1024 + threadIdx.x * 4;
    if (base >= a.n[i]) return;
    float4 v = *(const float4*)(a.src[i] + base);
    ushort4 o;
    o.x = f2bf(v.x); o.y = f2bf(v.y); o.z = f2bf(v.z); o.w = f2bf(v.w);
    *(ushort4*)(a.dst[i] + base) = o;
}

__device__ __forceinline__ float block_sum(float v, float* red) {
    #pragma unroll
    for (int off = 32; off > 0; off >>= 1) v += __shfl_down(v, off);
    __syncthreads();
    if ((threadIdx.x & 63) == 0) red[threadIdx.x >> 6] = v;
    __syncthreads();
    return red[0] + red[1] + red[2] + red[3];
}

__device__ __forceinline__ void pn_body(const float* __restrict__ P,
                                        u16* __restrict__ Pn, int row, float* red)
{
    const int t = threadIdx.x;
    float v[3];
    #pragma unroll
    for (int i = 0; i < 3; i++)
        v[i] = P[(size_t)row * 768 + t + i * 256];
    float tot = block_sum(v[0]*v[0] + v[1]*v[1] + v[2]*v[2], red);
    float inv = rsqrtf(tot);
    #pragma unroll
    for (int i = 0; i < 3; i++)
        Pn[(size_t)row * 768 + t + i * 256] = f2bf(v[i] * inv);
}

template<bool NORM>
__device__ __forceinline__ void ln_body(const float* __restrict__ xin,
                                        const float* __restrict__ g,
                                        const float* __restrict__ bta,
                                        u16* __restrict__ out,
                                        float* __restrict__ invnorm,
                                        int row, float* red)
{
    const int t = threadIdx.x;
    float v[3];
    #pragma unroll
    for (int i = 0; i < 3; i++)
        v[i] = xin[(size_t)row * 768 + t + i * 256];
    float tot = block_sum(v[0] + v[1] + v[2], red);
    float mu  = tot * (1.0f / 768.0f);
    float d0 = v[0] - mu, d1 = v[1] - mu, d2 = v[2] - mu;
    float tot2 = block_sum(d0 * d0 + d1 * d1 + d2 * d2, red);
    float rstd = rsqrtf(tot2 * (1.0f / 768.0f) + 1e-5f);
    float ss = 0.0f;
    #pragma unroll
    for (int i = 0; i < 3; i++) {
        int c = t + i * 256;
        float yy = (v[i] - mu) * rstd * g[c] + bta[c];
        out[(size_t)row * 768 + c] = f2bf(yy);
        ss += yy * yy;
    }
    if constexpr (NORM) {
        float tot3 = block_sum(ss, red);
        if (t == 0) invnorm[row] = rsqrtf(tot3);
    }
}

// fused prologue: conv (weights) + pn (P rows) + ln1 (x) in one launch
struct PrepArgs {
    ConvArgs conv;
    const float* P;   u16* Pn;
    const float* x;   const float* g; const float* bta;
    u16* n1;          float* invn;
    int conv_blocks;
};

__global__ __launch_bounds__(256)
void prep_k(PrepArgs pa)
{
    __shared__ float red[4];
    const int b = blockIdx.x;
    if (b < pa.conv_blocks) {
        conv_body(pa.conv, b);
    } else if (b < pa.conv_blocks + 64) {
        pn_body(pa.P, pa.Pn, b - pa.conv_blocks, red);
    } else {
        ln_body<true>(pa.x, pa.g, pa.bta, pa.n1, pa.invn,
                      b - pa.conv_blocks - 64, red);
    }
}

// standalone LN (step 12)
template<bool NORM>
__global__ __launch_bounds__(256)
void ln_k(const float* __restrict__ xin, const float* __restrict__ g,
          const float* __restrict__ bta, u16* __restrict__ out,
          float* __restrict__ invnorm)
{
    __shared__ float red[4];
    ln_body<NORM>(xin, g, bta, out, invnorm, blockIdx.x, red);
}

// ---------------- MFMA GEMM body: C[M,N] = A[M,K] * W[N,K]^T ---------------
// 128x128 tile, BK=32; 4 waves, each a 64x64 sub-tile. Triple-buffered LDS,
// 2-deep prefetch, one barrier per K-iter. XCD-chunked block order with
// intra-chunk col-grouping (G=6). smem_ = 3*8192 u16 (48 KB).
template<int FLAGS>
__device__ __forceinline__
void gemm_body(int orig, int nbx, int nby,
               const u16* __restrict__ A, const u16* __restrict__ W,
               const float* __restrict__ bias,
               const u16* __restrict__ res1, const float* __restrict__ resf,
               u16* __restrict__ out, float* __restrict__ outf,
               int M, int N, int K, u16* smem_)
{
    const int t = threadIdx.x;
    const int wave = t >> 6, lane = t & 63;
    const int cpx  = (nbx * nby) >> 3;         // wgs per XCD chunk
    const int xcd  = orig & 7, loc = orig >> 3;
    const int Rc   = cpx / nbx;                // rows per chunk
    const int gsz  = 6 * Rc;                   // wgs per col-group
    const int grp  = loc / gsz;
    const int rem  = loc - grp * gsz;
    const int ccol = grp * 6 + rem % 6;
    const int crow = xcd * Rc + rem / 6;
    const int m0 = crow * 128, n0 = ccol * 128;
    const int Wm = (wave >> 1) * 64, Wn = (wave & 1) * 64;
    const int rr = lane >> 2, cc = (lane & 3) * 8;
    const int quad = lane >> 4, r16 = lane & 15;
    const int NK = K >> 5;

    f32x4 acc[4][4];
    #pragma unroll
    for (int i = 0; i < 4; i++)
        #pragma unroll
        for (int j = 0; j < 4; j++)
            acc[i][j] = (f32x4){0.f, 0.f, 0.f, 0.f};

    // prologue: stage k-tiles 0 and 1 into bufs 0,1 (order matters for vmcnt)
    #pragma unroll
    for (int c = 0; c < 2; c++) {
        const int chunk = wave * 2 + c;
        const int row = chunk * 16 + rr;
        gload16(A + (size_t)(m0 + row) * K + cc, smem_ + chunk * 512);
        gload16(W + (size_t)(n0 + row) * K + cc, smem_ + 4096 + chunk * 512);
    }
    if (NK > 1) {
        #pragma unroll
        for (int c = 0; c < 2; c++) {
            const int chunk = wave * 2 + c;
            const int row = chunk * 16 + rr;
            gload16(A + (size_t)(m0 + row) * K + 32 + cc, smem_ + 8192 + chunk * 512);
            gload16(W + (size_t)(n0 + row) * K + 32 + cc, smem_ + 12288 + chunk * 512);
        }
    }

    for (int kt = 0; kt < NK; kt++) {
        const int cur = kt % 3;
        if (kt + 1 < NK)
            asm volatile("s_waitcnt vmcnt(4)\n\ts_barrier" ::: "memory");
        else
            asm volatile("s_waitcnt vmcnt(0)\n\ts_barrier" ::: "memory");
        if (kt + 2 < NK) {
            const int k0 = (kt + 2) * 32;
            const int nb = (kt + 2) % 3;
            #pragma unroll
            for (int c = 0; c < 2; c++) {
                const int chunk = wave * 2 + c;
                const int row = chunk * 16 + rr;
                gload16(A + (size_t)(m0 + row) * K + k0 + cc,
                        smem_ + nb * 8192 + chunk * 512);
                gload16(W + (size_t)(n0 + row) * K + k0 + cc,
                        smem_ + nb * 8192 + 4096 + chunk * 512);
            }
        }
        short8 af[4], bfr[4];
        #pragma unroll
        for (int i = 0; i < 4; i++) {
            af[i]  = *(const short8*)&smem_[cur * 8192 + (Wm + i * 16 + r16) * 32 + quad * 8];
            bfr[i] = *(const short8*)&smem_[cur * 8192 + 4096 + (Wn + i * 16 + r16) * 32 + quad * 8];
        }
        #pragma unroll
        for (int i = 0; i < 4; i++)
            #pragma unroll
            for (int j = 0; j < 4; j++)
                acc[i][j] = __builtin_amdgcn_mfma_f32_16x16x32_bf16(
                    af[i], bfr[j], acc[i][j], 0, 0, 0);
    }
    __syncthreads();

    // ---- epilogue: wave-private fp32 repack (no cross-wave sync) ----
    float* myl = (float*)smem_ + wave * 1088;   // 16 rows x 68 cols fp32
    float bj[4];
    #pragma unroll
    for (int j = 0; j < 4; j++) {
        if constexpr (FLAGS & F_BIAS) bj[j] = bias[n0 + Wn + j * 16 + r16];
        else bj[j] = 0.0f;
    }
    const int row = lane >> 2, seg = (lane & 3) * 16;

    #pragma unroll
    for (int i = 0; i < 4; i++) {
        #pragma unroll
        for (int j = 0; j < 4; j++)
            #pragma unroll
            for (int r = 0; r < 4; r++) {
                float v = acc[i][j][r] + bj[j];
                if constexpr (FLAGS & F_GELU) v = gelu_fast(v);
                myl[(quad * 4 + r) * 68 + j * 16 + r16] = v;
            }
        float v[16];
        #pragma unroll
        for (int k4 = 0; k4 < 4; k4++) {
            float4 f = *(const float4*)&myl[row * 68 + seg + k4 * 4];
            v[k4 * 4 + 0] = f.x; v[k4 * 4 + 1] = f.y;
            v[k4 * 4 + 2] = f.z; v[k4 * 4 + 3] = f.w;
        }
        const int m = m0 + Wm + i * 16 + row;
        const size_t idx = (size_t)m * N + n0 + Wn + seg;
        if constexpr (FLAGS & F_RES1) {
            ushort8v r0 = *(const ushort8v*)(res1 + idx);
            ushort8v r1 = *(const ushort8v*)(res1 + idx + 8);
            #pragma unroll
            for (int k = 0; k < 8; k++) { v[k] += bf2f(r0[k]); v[k + 8] += bf2f(r1[k]); }
        }
        if constexpr (FLAGS & F_RESF) {
            #pragma unroll
            for (int k4 = 0; k4 < 4; k4++) {
                float4 f = *(const float4*)(resf + idx + k4 * 4);
                v[k4 * 4 + 0] += f.x; v[k4 * 4 + 1] += f.y;
                v[k4 * 4 + 2] += f.z; v[k4 * 4 + 3] += f.w;
            }
        }
        if constexpr (FLAGS & F_OUTB) {
            ushort8v o0, o1;
            #pragma unroll
            for (int k = 0; k < 8; k++) { o0[k] = f2bf(v[k]); o1[k] = f2bf(v[k + 8]); }
            *(ushort8v*)(out + idx) = o0;
            *(ushort8v*)(out + idx + 8) = o1;
        }
        if constexpr (FLAGS & F_OUTF) {
            #pragma unroll
            for (int k4 = 0; k4 < 4; k4++) {
                float4 f = {v[k4 * 4 + 0], v[k4 * 4 + 1], v[k4 * 4 + 2], v[k4 * 4 + 3]};
                *(float4*)(outf + idx + k4 * 4) = f;
            }
        }
    }
}

template<int FLAGS>
__global__ __launch_bounds__(256)
void gemm_mfma(const u16* __restrict__ A, const u16* __restrict__ W,
               const float* __restrict__ bias,
               const u16* __restrict__ res1, const float* __restrict__ resf,
               u16* __restrict__ out, float* __restrict__ outf,
               int M, int N, int K)
{
    __shared__ u16 smem[3][8192];
    gemm_body<FLAGS>(blockIdx.x + blockIdx.y * gridDim.x, gridDim.x, gridDim.y,
                     A, W, bias, res1, resf, out, outf, M, N, K, &smem[0][0]);
}

// proj (K=768) and zin (K=64) co-resident: blocks [0,384) proj, [384,768) zin.
__global__ __launch_bounds__(256)
void gemm_pair_k(const u16* __restrict__ A0, const u16* __restrict__ W0,
                 const float* __restrict__ b0, u16* __restrict__ o0, int K0,
                 const u16* __restrict__ A1, const u16* __restrict__ W1,
                 const float* __restrict__ b1, u16* __restrict__ o1, int K1)
{
    __shared__ u16 smem[3][8192];
    if (blockIdx.x < 384)
        gemm_body<F_BIAS | F_OUTB>(blockIdx.x, 6, 64, A0, W0, b0,
                                   nullptr, nullptr, o0, nullptr,
                                   8192, 768, K0, &smem[0][0]);
    else
        gemm_body<F_BIAS | F_OUTB>(blockIdx.x - 384, 6, 64, A1, W1, b1,
                                   nullptr, nullptr, o1, nullptr,
                                   8192, 768, K1, &smem[0][0]);
}

// ---------------- dmap body: dmap=(n1@Pn^T)*invn ; cph=gelu(dmap@W1^T+b) ---
// Shared arrays carved from the caller's 48 KB block:
//   Asm f32[16][68] | Wsm f32[16][68] | Dsm u16[64][66] | W1s u16[64][66]
__device__ void dmap_body(const u16* __restrict__ A, const u16* __restrict__ Pn,
                          const float* __restrict__ invn,
                          const u16* __restrict__ w1, const float* __restrict__ b1,
                          float* __restrict__ dmap_f, u16* __restrict__ cph,
                          int blk, u16* smembase)
{
    float* Asm = (float*)smembase;          // [16][68]
    float* Wsm = Asm + 16 * 68;             // [16][68]
    u16*   Dsm = (u16*)(Wsm + 16 * 68);     // [64][66]
    u16*   W1s = Dsm + 64 * 66;             // [64][66]
    const int t  = threadIdx.x;
    const int tx = t & 15, ty = t >> 4;
    const int m0 = blk * 64;

    {
        const int r = t >> 2, c = (t & 3) * 16;
        #pragma unroll
        for (int k = 0; k < 16; k++)
            W1s[r * 66 + c + k] = w1[r * 64 + c + k];
    }

    float acc[4][4];
    #pragma unroll
    for (int i = 0; i < 4; i++)
        #pragma unroll
        for (int j = 0; j < 4; j++) acc[i][j] = 0.0f;

    for (int k0 = 0; k0 < 768; k0 += 16) {
        {
            int r = t >> 2, c4 = (t & 3) << 2;
            uint2 u = *(const uint2*)(A + (size_t)(m0 + r) * 768 + k0 + c4);
            Asm[(c4 + 0) * 68 + r] = bf2f(u.x & 0xffffu);
            Asm[(c4 + 1) * 68 + r] = bf2f(u.x >> 16);
            Asm[(c4 + 2) * 68 + r] = bf2f(u.y & 0xffffu);
            Asm[(c4 + 3) * 68 + r] = bf2f(u.y >> 16);
        }
        {
            int r = t >> 2, c4 = (t & 3) << 2;
            uint2 u = *(const uint2*)(Pn + (size_t)r * 768 + k0 + c4);
            Wsm[(c4 + 0) * 68 + r] = bf2f(u.x & 0xffffu);
            Wsm[(c4 + 1) * 68 + r] = bf2f(u.x >> 16);
            Wsm[(c4 + 2) * 68 + r] = bf2f(u.y & 0xffffu);
            Wsm[(c4 + 3) * 68 + r] = bf2f(u.y >> 16);
        }
        __syncthreads();
        #pragma unroll
        for (int k = 0; k < 16; k++) {
            float a[4], w[4];
            float4 va = *(const float4*)&Asm[k * 68 + ty * 4];
            a[0] = va.x; a[1] = va.y; a[2] = va.z; a[3] = va.w;
            float4 vw = *(const float4*)&Wsm[k * 68 + tx * 4];
            w[0] = vw.x; w[1] = vw.y; w[2] = vw.z; w[3] = vw.w;
            #pragma unroll
            for (int i = 0; i < 4; i++)
                #pragma unroll
                for (int j = 0; j < 4; j++)
                    acc[i][j] = fmaf(a[i], w[j], acc[i][j]);
        }
        __syncthreads();
    }

    #pragma unroll
    for (int i = 0; i < 4; i++) {
        const int m = m0 + ty * 4 + i;
        const float rs = invn[m];
        float4 o4;
        float e0 = acc[i][0] * rs, e1 = acc[i][1] * rs;
        float e2 = acc[i][2] * rs, e3 = acc[i][3] * rs;
        o4.x = e0; o4.y = e1; o4.z = e2; o4.w = e3;
        *(float4*)(dmap_f + (size_t)m * 64 + tx * 4) = o4;
        const int rl = ty * 4 + i;
        Dsm[rl * 66 + tx * 4 + 0] = f2bf(e0);
        Dsm[rl * 66 + tx * 4 + 1] = f2bf(e1);
        Dsm[rl * 66 + tx * 4 + 2] = f2bf(e2);
        Dsm[rl * 66 + tx * 4 + 3] = f2bf(e3);
    }
    __syncthreads();

    float acc2[4][4];
    #pragma unroll
    for (int i = 0; i < 4; i++)
        #pragma unroll
        for (int j = 0; j < 4; j++) acc2[i][j] = 0.0f;
    for (int k4 = 0; k4 < 16; k4++) {
        float d[4][4], w[4][4];
        #pragma unroll
        for (int i = 0; i < 4; i++) {
            u32 u0 = *(const u32*)&Dsm[(ty * 4 + i) * 66 + k4 * 4];
            u32 u1 = *(const u32*)&Dsm[(ty * 4 + i) * 66 + k4 * 4 + 2];
            d[i][0] = bf2f(u0 & 0xffffu); d[i][1] = bf2f(u0 >> 16);
            d[i][2] = bf2f(u1 & 0xffffu); d[i][3] = bf2f(u1 >> 16);
        }
        #pragma unroll
        for (int j = 0; j < 4; j++) {
            u32 u0 = *(const u32*)&W1s[(tx * 4 + j) * 66 + k4 * 4];
            u32 u1 = *(const u32*)&W1s[(tx * 4 + j) * 66 + k4 * 4 + 2];
            w[j][0] = bf2f(u0 & 0xffffu); w[j][1] = bf2f(u0 >> 16);
            w[j][2] = bf2f(u1 & 0xffffu); w[j][3] = bf2f(u1 >> 16);
        }
        #pragma unroll
        for (int i = 0; i < 4; i++)
            #pragma unroll
            for (int j = 0; j < 4; j++)
                #pragma unroll
                for (int kk = 0; kk < 4; kk++)
                    acc2[i][j] = fmaf(d[i][kk], w[j][kk], acc2[i][j]);
    }
    {
        float4 bv = *(const float4*)(b1 + tx * 4);
        float b4[4] = {bv.x, bv.y, bv.z, bv.w};
        #pragma unroll
        for (int i = 0; i < 4; i++) {
            const int m = m0 + ty * 4 + i;
            ushort4 o4;
            o4.x = f2bf(gelu_exact(acc2[i][0] + b4[0]));
            o4.y = f2bf(gelu_exact(acc2[i][1] + b4[1]));
            o4.z = f2bf(gelu_exact(acc2[i][2] + b4[2]));
            o4.w = f2bf(gelu_exact(acc2[i][3] + b4[3]));
            *(ushort4*)(cph + (size_t)m * 64 + tx * 4) = o4;
        }
    }
}

// merged launch: blocks [0,128) = dmap branch (starts at t=0, hidden under
// qkv); blocks [128,1280) = qkv GEMM on a virtual (18,64) grid.
__global__ __launch_bounds__(256)
void qkv_dmap_k(const u16* __restrict__ A, const u16* __restrict__ Wq,
                const float* __restrict__ bq, u16* __restrict__ outq,
                const u16* __restrict__ Pn, const float* __restrict__ invn,
                const u16* __restrict__ w1, const float* __restrict__ b1,
                float* __restrict__ dmap_f, u16* __restrict__ cph)
{
    __shared__ u16 smem[3][8192];
    if (blockIdx.x < 128)
        dmap_body(A, Pn, invn, w1, b1, dmap_f, cph, blockIdx.x, &smem[0][0]);
    else
        gemm_body<F_BIAS | F_OUTB>(blockIdx.x - 128, 18, 64, A, Wq, bq,
                                   nullptr, nullptr, outq, nullptr,
                                   8192, 2304, 768, &smem[0][0]);
}

// ---------------- MFMA flash attention (bf16, max-free online softmax) ----
__global__ __launch_bounds__(256)
void attn_mfma(const u16* __restrict__ qkv, u16* __restrict__ out)
{
    const int orig = blockIdx.x + blockIdx.y * 8;
    const int wg   = (orig & 7) * 96 + (orig >> 3);
    const int qt = wg & 7;                // 0..7  (128-row q tiles)
    const int bh = wg >> 3;               // 0..95
    const int b = bh / 12, h = bh % 12;
    __shared__ u16 Qs[2 * 128 * 32];      // 16 KB
    __shared__ u16 Ks[2 * 64 * 32];       //  8 KB
    __shared__ u16 Vt[2 * 64 * 32];       //  8 KB  (transposed: rows = d)
    __shared__ u16 Ps[2 * 128 * 32];      // 16 KB; epilogue: 4 waves x 2 x 16x64
    const int t = threadIdx.x;
    const int wave = t >> 6, lane = t & 63;
    const int quad = lane >> 4, r16 = lane & 15;
    const size_t RS = 2304;
    const int tok0 = b * 1024 + qt * 128;
    const u16* qbase = qkv + (size_t)tok0 * RS + h * 64;
    const float SC = 0.125f * 1.44269504088896340736f;   // scale * log2(e)

    #pragma unroll
    for (int c = 0; c < 4; c++) {
        int idx = wave * 4 + c;
        int kc = idx >> 3, rg = idx & 7;
        int row = rg * 16 + (lane >> 2);
        gload16(qbase + (size_t)row * RS + kc * 32 + (lane & 3) * 8,
                &Qs[kc * 4096 + rg * 512]);
    }

    f32x4 O[2][4];
    float lpart[2][4];
    #pragma unroll
    for (int i = 0; i < 2; i++)
        #pragma unroll
        for (int j = 0; j < 4; j++) {
            O[i][j] = (f32x4){0.f, 0.f, 0.f, 0.f};
            lpart[i][j & 3] = 0.0f;
        }

    // staging helpers
    const int kp = t & 63, dg = t >> 6;
    const int vb = (kp >> 5) * 2048 + (kp & 31);
    uint2 vr[4];

    // prologue: stage kt=0 (K-DMA into Ks, V into regs)
    {
        const u16* kbase = qkv + (size_t)(b * 1024) * RS + 768 + h * 64;
        #pragma unroll
        for (int c = 0; c < 2; c++) {
            int idx = wave * 2 + c;
            int kc = idx >> 2, rg = idx & 3;
            int row = rg * 16 + (lane >> 2);
            gload16(kbase + (size_t)row * RS + kc * 32 + (lane & 3) * 8,
                    &Ks[kc * 2048 + rg * 512]);
        }
        const u16* vbase = qkv + (size_t)(b * 1024) * RS + 1536 + h * 64;
        #pragma unroll
        for (int it = 0; it < 4; it++) {
            int d0 = dg * 16 + it * 4;
            vr[it] = *(const uint2*)(vbase + (size_t)kp * RS + d0);
        }
    }

    for (int kt = 0; kt < 16; kt++) {
        __syncthreads();
        #pragma unroll
        for (int it = 0; it < 4; it++) {
            int d0 = dg * 16 + it * 4;
            uint2 u = vr[it];
            Vt[vb + (d0 + 0) * 32] = (u16)(u.x & 0xffffu);
            Vt[vb + (d0 + 1) * 32] = (u16)(u.x >> 16);
            Vt[vb + (d0 + 2) * 32] = (u16)(u.y & 0xffffu);
            Vt[vb + (d0 + 3) * 32] = (u16)(u.y >> 16);
        }

        f32x4 S[2][4];
        #pragma unroll
        for (int i = 0; i < 2; i++)
            #pragma unroll
            for (int j = 0; j < 4; j++)
                S[i][j] = (f32x4){0.f, 0.f, 0.f, 0.f};
        __builtin_amdgcn_s_setprio(1);
        #pragma unroll
        for (int kc = 0; kc < 2; kc++) {
            short8 aq[2], bk[4];
            #pragma unroll
            for (int i = 0; i < 2; i++)
                aq[i] = *(const short8*)&Qs[kc * 4096 + (wave * 32 + i * 16 + r16) * 32 + quad * 8];
            #pragma unroll
            for (int j = 0; j < 4; j++)
                bk[j] = *(const short8*)&Ks[kc * 2048 + (j * 16 + r16) * 32 + quad * 8];
            #pragma unroll
            for (int i = 0; i < 2; i++)
                #pragma unroll
                for (int j = 0; j < 4; j++)
                    S[i][j] = __builtin_amdgcn_mfma_f32_16x16x32_bf16(
                        aq[i], bk[j], S[i][j], 0, 0, 0);
        }
        __builtin_amdgcn_s_setprio(0);

        #pragma unroll
        for (int i = 0; i < 2; i++) {
            #pragma unroll
            for (int j = 0; j < 4; j++) {
                const int col = j * 16 + r16;
                const int pb = (col >> 5) * 4096 + (col & 31);
                #pragma unroll
                for (int r = 0; r < 4; r++) {
                    float p = __builtin_amdgcn_exp2f(S[i][j][r] * SC);
                    lpart[i][r] += p;
                    const int row = wave * 32 + i * 16 + quad * 4 + r;
                    Ps[pb + row * 32] = f2bf_fast(p);
                }
            }
        }

        __syncthreads();

        if (kt < 15) {
            const u16* kbase = qkv + (size_t)(b * 1024 + (kt + 1) * 64) * RS + 768 + h * 64;
            #pragma unroll
            for (int c = 0; c < 2; c++) {
                int idx = wave * 2 + c;
                int kc = idx >> 2, rg = idx & 3;
                int row = rg * 16 + (lane >> 2);
                gload16(kbase + (size_t)row * RS + kc * 32 + (lane & 3) * 8,
                        &Ks[kc * 2048 + rg * 512]);
            }
            const u16* vbase = qkv + (size_t)(b * 1024 + (kt + 1) * 64) * RS + 1536 + h * 64;
            #pragma unroll
            for (int it = 0; it < 4; it++) {
                int d0 = dg * 16 + it * 4;
                vr[it] = *(const uint2*)(vbase + (size_t)kp * RS + d0);
            }
        }

        __builtin_amdgcn_s_setprio(1);
        #pragma unroll
        for (int kc = 0; kc < 2; kc++) {
            short8 ap[2], bv[4];
            #pragma unroll
            for (int i = 0; i < 2; i++)
                ap[i] = *(const short8*)&Ps[kc * 4096 + (wave * 32 + i * 16 + r16) * 32 + quad * 8];
            #pragma unroll
            for (int j = 0; j < 4; j++)
                bv[j] = *(const short8*)&Vt[kc * 2048 + (j * 16 + r16) * 32 + quad * 8];
            #pragma unroll
            for (int i = 0; i < 2; i++)
                #pragma unroll
                for (int j = 0; j < 4; j++)
                    O[i][j] = __builtin_amdgcn_mfma_f32_16x16x32_bf16(
                        ap[i], bv[j], O[i][j], 0, 0, 0);
        }
        __builtin_amdgcn_s_setprio(0);
    }

    // epilogue: wave-private repack through Ps (dead), coalesced 16B stores
    const int row = lane >> 2, seg = (lane & 3) * 16;
    #pragma unroll
    for (int i = 0; i < 2; i++) {
        float linv[4];
        #pragma unroll
        for (int r = 0; r < 4; r++) {
            float l = lpart[i][r];
            l += __shfl_xor(l, 1);
            l += __shfl_xor(l, 2);
            l += __shfl_xor(l, 4);
            l += __shfl_xor(l, 8);
            linv[r] = 1.0f / l;
        }
        u16* myl = &Ps[wave * 2048 + i * 1024];   // 16 rows x 64 cols
        #pragma unroll
        for (int j = 0; j < 4; j++)
            #pragma unroll
            for (int r = 0; r < 4; r++)
                myl[(quad * 4 + r) * 64 + j * 16 + r16] = f2bf(O[i][j][r] * linv[r]);
        const int token = tok0 + wave * 32 + i * 16 + row;
        const size_t oidx = (size_t)token * 768 + h * 64 + seg;
        *(ushort8v*)(out + oidx)     = *(const ushort8v*)&myl[row * 64 + seg];
        *(ushort8v*)(out + oidx + 8) = *(const ushort8v*)&myl[row * 64 + seg + 8];
    }
}

// ---------------------------------------------------------------------------
extern "C" void kernel_launch(void* const* d_in, const int* in_sizes, int n_in,
                              void* d_out, int out_size, void* d_ws, size_t ws_size,
                              hipStream_t stream)
{
    (void)in_sizes; (void)n_in; (void)out_size; (void)ws_size;
    const float* x        = (const float*)d_in[0];
    const float* ln1_g    = (const float*)d_in[1];
    const float* ln1_b    = (const float*)d_in[2];
    const float* qkv_w    = (const float*)d_in[3];
    const float* qkv_b    = (const float*)d_in[4];
    const float* proj_w   = (const float*)d_in[5];
    const float* proj_b   = (const float*)d_in[6];
    const float* c_qkv_w  = (const float*)d_in[7];
    const float* c_qkv_b  = (const float*)d_in[8];
    const float* c_proj_w = (const float*)d_in[9];
    const float* c_proj_b = (const float*)d_in[10];
    const float* cp_fc1_w = (const float*)d_in[11];
    const float* cp_fc1_b = (const float*)d_in[12];
    const float* cp_fc2_w = (const float*)d_in[13];
    const float* cp_fc2_b = (const float*)d_in[14];
    const float* P        = (const float*)d_in[15];
    const float* ln2_g    = (const float*)d_in[16];
    const float* ln2_b    = (const float*)d_in[17];
    const float* fc1_w    = (const float*)d_in[18];
    const float* fc1_b    = (const float*)d_in[19];
    const float* fc2_w    = (const float*)d_in[20];
    const float* fc2_b    = (const float*)d_in[21];

    float* out_x    = (float*)d_out;               // (8,1024,768) fp32
    float* out_dmap = out_x + 6291456;             // (8,1024,64)  fp32

    // ws layout (u16 element units)
    u16* us    = (u16*)d_ws;
    u16* n1n2  = us;                         //  6291456  n1 -> zin -> n2
    u16* bigA  = us + 6291456;               // 25165824  qkv/qkv2 ; h(3072)
    u16* ao    = bigA + 18874368;            //  6291456  attn out (tail)
    u16* y     = us + 31457280;              //  6291456
    float* xs  = (float*)(us + 37748736);    //  6291456 fp32
    u16* cph   = us + 50855936;              //   524288
    u16* Pn    = us + 51380224;              //    49152
    float* invn = (float*)(us + 51429376);   //  8192 fp32
    u16* ci    = us + 51445760;              //  canonical bf16 weights

    u16* w_qkv   = ci;                  // 1769472
    u16* w_proj  = ci + 1769472;        // 589824
    u16* w_cqkv  = ci + 2359296;        // 1769472
    u16* w_cproj = ci + 4128768;        // 589824
    u16* w_cpf1  = ci + 4718592;        // 4096
    u16* w_cpf2  = ci + 4722688;        // 49152
    u16* w_fc1   = ci + 4771840;        // 2359296
    u16* w_fc2   = ci + 7131136;        // 2359296

    // 0-2. fused prologue: weight conv + P-normalize + LN1
    {
        PrepArgs pa;
        const float* wsrc[8] = { qkv_w, proj_w, c_qkv_w, c_proj_w,
                                 cp_fc1_w, cp_fc2_w, fc1_w, fc2_w };
        u16* wdst[8] = { w_qkv, w_proj, w_cqkv, w_cproj,
                         w_cpf1, w_cpf2, w_fc1, w_fc2 };
        const int wn[8] = { 1769472, 589824, 1769472, 589824,
                            4096, 49152, 2359296, 2359296 };
        int cum = 0;
        for (int i = 0; i < 8; i++) {
            pa.conv.src[i] = wsrc[i]; pa.conv.dst[i] = wdst[i];
            pa.conv.n[i] = wn[i];
            pa.conv.nblk[i] = cum;
            cum += (wn[i] / 4 + 255) / 256;
        }
        pa.conv.nblk[8] = cum;
        pa.conv_blocks = cum;
        pa.P = P; pa.Pn = Pn;
        pa.x = x; pa.g = ln1_g; pa.bta = ln1_b;
        pa.n1 = n1n2; pa.invn = invn;
        prep_k<<<cum + 64 + 8192, 256, 0, stream>>>(pa);
    }

    // 3 + dmap branch, co-resident: qkv GEMM || (dmap fp32 + cph)
    qkv_dmap_k<<<1280, 256, 0, stream>>>(n1n2, w_qkv, qkv_b, bigA,
                                         Pn, invn, w_cpf1, cp_fc1_b,
                                         out_dmap, cph);
    // 4. attention 1
    attn_mfma<<<dim3(8, 96), 256, 0, stream>>>(bigA, ao);
    // 5+8. co-resident: y = ao @ proj_w^T + b  ||  zin = cph @ cp_fc2_w^T + b
    //      (zin overwrites n1n2; its readers qkv/dmap completed above)
    gemm_pair_k<<<768, 256, 0, stream>>>(ao, w_proj, proj_b, y, 768,
                                         cph, w_cpf2, cp_fc2_b, n1n2, 64);
    // 9. qkv2 = zin @ c_qkv_w^T + b
    gemm_mfma<F_BIAS | F_OUTB>
        <<<dim3(18, 64), 256, 0, stream>>>(n1n2, w_cqkv, c_qkv_b, nullptr, nullptr,
                                           bigA, nullptr, 8192, 2304, 768);
    // 10. attention 2
    attn_mfma<<<dim3(8, 96), 256, 0, stream>>>(bigA, ao);
    // 11. xs = ao2 @ c_proj_w^T + b + y + x   (y bf16, x fp32) -> fp32
    gemm_mfma<F_BIAS | F_RES1 | F_RESF | F_OUTF>
        <<<dim3(6, 64), 256, 0, stream>>>(ao, w_cproj, c_proj_b, y, x,
                                          nullptr, xs, 8192, 768, 768);
    // 12. n2 = LN(xs)
    ln_k<false><<<8192, 256, 0, stream>>>(xs, ln2_g, ln2_b, n1n2, nullptr);
    // 13. h = gelu(n2 @ fc1_w^T + b)
    gemm_mfma<F_BIAS | F_GELU | F_OUTB>
        <<<dim3(24, 64), 256, 0, stream>>>(n1n2, w_fc1, fc1_b, nullptr, nullptr,
                                           bigA, nullptr, 8192, 3072, 768);
    // 14. out = h @ fc2_w^T + b + xs  -> fp32 d_out
    gemm_mfma<F_BIAS | F_RESF | F_OUTF>
        <<<dim3(6, 64), 256, 0, stream>>>(bigA, w_fc2, fc2_b, nullptr, xs,
                                          nullptr, out_x, 8192, 768, 3072);
}